// Round 6
// baseline (1639.480 us; speedup 1.0000x reference)
//
#include <hip/hip_runtime.h>

#define N_NODES 50000
#define MPAD    50048           // N_NODES rounded up to 128
#define IN_F    64
#define HIDDEN  512
#define N_EDGES 160000
#define N_TRAIN 80000
#define N_CLASS 7
#define BN_EPS  1e-5f

#define MT      (MPAD / 128)    // 391 m-tiles
#define NT      4               // 128-col n-tiles
#define FULLGRP ((MT / 8) * 32) // 1536: full 8-mtile x 4-ntile swizzle groups

typedef short  bf16x8 __attribute__((ext_vector_type(8)));
typedef float  f32x4  __attribute__((ext_vector_type(4)));
typedef unsigned short ushort_t;

// ---- bf16 helpers (manual RNE; values are finite) -------------------------
__device__ __forceinline__ ushort_t f2b(float v) {
    union { float f; unsigned int u; } c; c.f = v;
    unsigned int x = c.u;
    unsigned int r = (x + 0x7FFFu + ((x >> 16) & 1u)) >> 16;
    return (ushort_t)r;
}
__device__ __forceinline__ float b2f(ushort_t b) {
    union { unsigned int u; float f; } c; c.u = ((unsigned int)b) << 16;
    return c.f;
}

// ===========================================================================
// CSR build: zero -> histogram(dst) -> exclusive scan -> scatter src ids
// ===========================================================================
__global__ void zero_kernel(int* __restrict__ p, int n) {
    int i = blockIdx.x * blockDim.x + threadIdx.x;
    if (i < n) p[i] = 0;
}

__global__ void hist_kernel(const int* __restrict__ ei, int* __restrict__ deg) {
    int e = blockIdx.x * blockDim.x + threadIdx.x;
    if (e >= N_EDGES) return;
    atomicAdd(&deg[ei[N_EDGES + e]], 1);
}

// single block, 1024 threads; rowptr[0]=0, rowptr[i+1]=incl_scan(deg)[i]
__global__ __launch_bounds__(1024) void scan_kernel(const int* __restrict__ deg,
                                                    int* __restrict__ rowptr) {
    __shared__ int buf[1024];
    __shared__ int carry_s;
    int tid = threadIdx.x;
    if (tid == 0) { carry_s = 0; rowptr[0] = 0; }
    __syncthreads();
    for (int base = 0; base < N_NODES; base += 1024) {
        int i = base + tid;
        buf[tid] = (i < N_NODES) ? deg[i] : 0;
        __syncthreads();
        for (int off = 1; off < 1024; off <<= 1) {
            int t = (tid >= off) ? buf[tid - off] : 0;
            __syncthreads();
            buf[tid] += t;
            __syncthreads();
        }
        if (i < N_NODES) rowptr[i + 1] = buf[tid] + carry_s;
        __syncthreads();
        if (tid == 0) carry_s += buf[1023];
        __syncthreads();
    }
}

__global__ void cursor_init_kernel(const int* __restrict__ rowptr,
                                   int* __restrict__ cursor) {
    int i = blockIdx.x * blockDim.x + threadIdx.x;
    if (i < N_NODES) cursor[i] = rowptr[i];
}

__global__ void scatter_kernel(const int* __restrict__ ei,
                               int* __restrict__ cursor, int* __restrict__ adj) {
    int e = blockIdx.x * blockDim.x + threadIdx.x;
    if (e >= N_EDGES) return;
    int src = ei[e], dst = ei[N_EDGES + e];
    int pos = atomicAdd(&cursor[dst], 1);
    adj[pos] = src;
}

// ===========================================================================
// Gather aggregation (CSR), fused scale + split-bf16 output.
// out[n] = (1+eps)*h[n] + sum_{k in row n} h[adj[k]]
// ===========================================================================
__global__ __launch_bounds__(256) void gather64_kernel(
    const float* __restrict__ x, const int* __restrict__ rowptr,
    const int* __restrict__ adj, const float* __restrict__ epsp,
    ushort_t* __restrict__ hi, ushort_t* __restrict__ lo) {
    int wave = threadIdx.x >> 6, lane = threadIdx.x & 63;
    int n = blockIdx.x * 4 + wave;
    if (n >= N_NODES) return;
    float s = 1.0f + *epsp;
    float sum = s * x[(size_t)n * IN_F + lane];
    int beg = rowptr[n], end = rowptr[n + 1];
    for (int k = beg; k < end; k++) {
        sum += x[(size_t)adj[k] * IN_F + lane];
    }
    ushort_t hb = f2b(sum);
    ushort_t lb = f2b(sum - b2f(hb));
    hi[(size_t)n * IN_F + lane] = hb;
    lo[(size_t)n * IN_F + lane] = lb;
}

__global__ __launch_bounds__(256) void gather512_kernel(
    const float* __restrict__ h, const int* __restrict__ rowptr,
    const int* __restrict__ adj, const float* __restrict__ epsp,
    ushort_t* __restrict__ hi, ushort_t* __restrict__ lo) {
    int wave = threadIdx.x >> 6, lane = threadIdx.x & 63;
    int n = blockIdx.x * 4 + wave;
    if (n >= N_NODES) return;
    float s = 1.0f + *epsp;
    const float* hn = h + (size_t)n * HIDDEN;
    const int f0 = lane * 4, f1 = 256 + lane * 4;
    float4 a0 = *(const float4*)&hn[f0];
    float4 a1 = *(const float4*)&hn[f1];
    float sum0[4] = {s * a0.x, s * a0.y, s * a0.z, s * a0.w};
    float sum1[4] = {s * a1.x, s * a1.y, s * a1.z, s * a1.w};
    int beg = rowptr[n], end = rowptr[n + 1];
    for (int k = beg; k < end; k++) {
        const float* hs = h + (size_t)adj[k] * HIDDEN;
        float4 b0 = *(const float4*)&hs[f0];
        float4 b1 = *(const float4*)&hs[f1];
        sum0[0] += b0.x; sum0[1] += b0.y; sum0[2] += b0.z; sum0[3] += b0.w;
        sum1[0] += b1.x; sum1[1] += b1.y; sum1[2] += b1.z; sum1[3] += b1.w;
    }
    ushort_t h4[4], l4[4];
#pragma unroll
    for (int j = 0; j < 4; j++) {
        h4[j] = f2b(sum0[j]);
        l4[j] = f2b(sum0[j] - b2f(h4[j]));
    }
    *(ushort4*)&hi[(size_t)n * HIDDEN + f0] = make_ushort4(h4[0], h4[1], h4[2], h4[3]);
    *(ushort4*)&lo[(size_t)n * HIDDEN + f0] = make_ushort4(l4[0], l4[1], l4[2], l4[3]);
#pragma unroll
    for (int j = 0; j < 4; j++) {
        h4[j] = f2b(sum1[j]);
        l4[j] = f2b(sum1[j] - b2f(h4[j]));
    }
    *(ushort4*)&hi[(size_t)n * HIDDEN + f1] = make_ushort4(h4[0], h4[1], h4[2], h4[3]);
    *(ushort4*)&lo[(size_t)n * HIDDEN + f1] = make_ushort4(l4[0], l4[1], l4[2], l4[3]);
}

// ---------------------------------------------------------------------------
// W[K][512] fp32 -> Wt_hi[512][K], Wt_lo[512][K] bf16 (transpose + split)
// ---------------------------------------------------------------------------
__global__ void wtrans_kernel(const float* __restrict__ W,
                              ushort_t* __restrict__ Whi,
                              ushort_t* __restrict__ Wlo, int K) {
    __shared__ float t[32][33];
    int tx = threadIdx.x & 31, ty = threadIdx.x >> 5;   // ty 0..7
    int nb = blockIdx.x * 32, kb = blockIdx.y * 32;
#pragma unroll
    for (int i = 0; i < 4; i++) {
        int k = kb + ty + i * 8;
        t[ty + i * 8][tx] = W[(size_t)k * HIDDEN + nb + tx];
    }
    __syncthreads();
#pragma unroll
    for (int i = 0; i < 4; i++) {
        int n = nb + ty + i * 8;
        int k = kb + tx;
        float v = t[tx][ty + i * 8];
        ushort_t hb = f2b(v);
        ushort_t lb = f2b(v - b2f(hb));
        Whi[(size_t)n * K + k] = hb;
        Wlo[(size_t)n * K + k] = lb;
    }
}

// ---------------------------------------------------------------------------
// Direct-fragment split-bf16 MFMA GEMM (NO LDS, NO barriers).
// C = epilogue(A @ B + bias), N = 512 fixed, K compile-time (64 or 512).
// A planes [MPAD][K] bf16 hi/lo; B planes [512][K] bf16 (transposed weights).
// 128x128 block tile, 4 waves 2x2, wave tile 64x64, 16x16x32 MFMA, 3-term
// split accumulate. Fragments are loaded straight from global: the gather
// A[(base+r)][k0+quad*8 ..+8] is 16 B/lane over 16 rows = 16 fully-used 64-B
// lines per instruction (same line count as coalesced; L2-resident after the
// XCD swizzle). No vmcnt(0)/s_barrier drain anywhere in the K-loop; compiler
// emits per-fragment vmcnt waits, unroll-2 interleaves next-iter loads above
// current-iter MFMAs.
// ---------------------------------------------------------------------------
template<int K>
__global__ __launch_bounds__(256) void gemm_direct_kernel(
    const ushort_t* __restrict__ Ahi, const ushort_t* __restrict__ Alo,
    const ushort_t* __restrict__ Bhi, const ushort_t* __restrict__ Blo,
    const float* __restrict__ bias,
    float* __restrict__ Cf, ushort_t* __restrict__ Chi, ushort_t* __restrict__ Clo,
    int mode,
    const float* __restrict__ bn_g, const float* __restrict__ bn_b,
    const float* __restrict__ bn_m, const float* __restrict__ bn_v) {
    const int tid  = threadIdx.x;
    const int wave = tid >> 6, lane = tid & 63;
    const int wm = wave >> 1, wn = wave & 1;
    const int quad = lane >> 4, r = lane & 15;

    // XCD-aware tile mapping (blocks round-robin over 8 XCDs; each XCD runs
    // one m-tile's 4 n-tiles back-to-back so the A rows stay in its L2)
    int idx = blockIdx.x, m_t, n_t;
    if (idx < FULLGRP) {
        m_t = (idx >> 5) * 8 + (idx & 7);
        n_t = (idx >> 3) & 3;
    } else {
        int t = idx - FULLGRP;
        m_t = (FULLGRP >> 2) + (t >> 2);
        n_t = t & 3;
    }
    const int m0 = m_t * 128, n0 = n_t * 128;

    const f32x4 vzero = {0.f, 0.f, 0.f, 0.f};
    f32x4 acc[4][4];
#pragma unroll
    for (int i = 0; i < 4; i++)
#pragma unroll
        for (int j = 0; j < 4; j++) acc[i][j] = vzero;

    // per-lane fragment base offsets (elements)
    const size_t aoff = (size_t)(m0 + wm * 64 + r) * K + quad * 8;
    const size_t boff = (size_t)(n0 + wn * 64 + r) * K + quad * 8;
    const ushort_t* Ah = Ahi + aoff;
    const ushort_t* Al = Alo + aoff;
    const ushort_t* Bh = Bhi + boff;
    const ushort_t* Bl = Blo + boff;
    const size_t rstep = (size_t)16 * K;   // 16 rows down

#pragma unroll 2
    for (int k0 = 0; k0 < K; k0 += 32) {
        bf16x8 ah[4], al[4], bh[4], bl[4];
#pragma unroll
        for (int i = 0; i < 4; i++) {
            ah[i] = *(const bf16x8*)(Ah + i * rstep + k0);
            al[i] = *(const bf16x8*)(Al + i * rstep + k0);
            bh[i] = *(const bf16x8*)(Bh + i * rstep + k0);
            bl[i] = *(const bf16x8*)(Bl + i * rstep + k0);
        }
#pragma unroll
        for (int i = 0; i < 4; i++)
#pragma unroll
            for (int j = 0; j < 4; j++) {
                acc[i][j] = __builtin_amdgcn_mfma_f32_16x16x32_bf16(ah[i], bh[j], acc[i][j], 0, 0, 0);
                acc[i][j] = __builtin_amdgcn_mfma_f32_16x16x32_bf16(ah[i], bl[j], acc[i][j], 0, 0, 0);
                acc[i][j] = __builtin_amdgcn_mfma_f32_16x16x32_bf16(al[i], bh[j], acc[i][j], 0, 0, 0);
            }
    }

    // ---- epilogue ----
    float bia[4], sc[4], sh[4];
#pragma unroll
    for (int j = 0; j < 4; j++) {
        int col = n0 + wn * 64 + j * 16 + r;
        bia[j] = bias[col];
        if (mode == 2) {
            float g = bn_g[col], bb = bn_b[col], mm = bn_m[col], vv = bn_v[col];
            sc[j] = g * rsqrtf(vv + BN_EPS);
            sh[j] = bb - mm * sc[j];
        } else { sc[j] = 1.f; sh[j] = 0.f; }
    }
#pragma unroll
    for (int i = 0; i < 4; i++) {
#pragma unroll
        for (int rg = 0; rg < 4; rg++) {
            int row = m0 + wm * 64 + i * 16 + quad * 4 + rg;
            if (row >= N_NODES) continue;
#pragma unroll
            for (int j = 0; j < 4; j++) {
                int col = n0 + wn * 64 + j * 16 + r;
                float v = acc[i][j][rg] + bia[j];
                if (mode >= 1) v = fmaxf(v, 0.f);
                if (mode == 2) v = v * sc[j] + sh[j];
                size_t oix = (size_t)row * HIDDEN + col;
                if (Cf) {
                    Cf[oix] = v;
                } else {
                    ushort_t hb = f2b(v);
                    ushort_t lb = f2b(v - b2f(hb));
                    Chi[oix] = hb;
                    Clo[oix] = lb;
                }
            }
        }
    }
}

// ---------------------------------------------------------------------------
// out[t] = (h[a_t] * h[b_t]) @ fc2_W + fc2_b ; one wave per train edge.
// ---------------------------------------------------------------------------
__global__ __launch_bounds__(256) void fc2_kernel(
    const float* __restrict__ h, const int* __restrict__ ei,
    const int* __restrict__ teid, const float* __restrict__ W,
    const float* __restrict__ bias, float* __restrict__ out) {
    __shared__ float Ws[HIDDEN * N_CLASS];
    __shared__ float bs[N_CLASS];
    for (int i = threadIdx.x; i < HIDDEN * N_CLASS; i += blockDim.x) Ws[i] = W[i];
    if (threadIdx.x < N_CLASS) bs[threadIdx.x] = bias[threadIdx.x];
    __syncthreads();

    int wave = threadIdx.x >> 6;
    int lane = threadIdx.x & 63;
    int t = blockIdx.x * 4 + wave;
    if (t >= N_TRAIN) return;

    int e = teid[t];
    int a = ei[e];
    int b = ei[N_EDGES + e];
    const float* xa = h + (size_t)a * HIDDEN;
    const float* xb = h + (size_t)b * HIDDEN;

    float acc[N_CLASS];
#pragma unroll
    for (int c = 0; c < N_CLASS; c++) acc[c] = 0.f;

    int j0 = lane * 8;
    float4 a0 = *(const float4*)&xa[j0];
    float4 a1 = *(const float4*)&xa[j0 + 4];
    float4 b0 = *(const float4*)&xb[j0];
    float4 b1 = *(const float4*)&xb[j0 + 4];
    float p[8] = {a0.x * b0.x, a0.y * b0.y, a0.z * b0.z, a0.w * b0.w,
                  a1.x * b1.x, a1.y * b1.y, a1.z * b1.z, a1.w * b1.w};
#pragma unroll
    for (int jj = 0; jj < 8; jj++) {
        const float* wrow = &Ws[(j0 + jj) * N_CLASS];
#pragma unroll
        for (int c = 0; c < N_CLASS; c++) acc[c] = fmaf(p[jj], wrow[c], acc[c]);
    }
#pragma unroll
    for (int c = 0; c < N_CLASS; c++) {
        float v = acc[c];
        for (int off = 32; off > 0; off >>= 1) v += __shfl_down(v, off, 64);
        if (lane == 0) out[(size_t)t * N_CLASS + c] = v + bs[c];
    }
}

// ---------------------------------------------------------------------------
// Workspace (~211.4 MB):
//   R0h R0l R1h R1l (4 bf16 planes) | weights | CSR {deg/cursor, rowptr, adj}
// Liveness chain:
//   gather64 -> H0 split (head of R1)          [x input]
//   gemm1: H0 -> h1 split (R0)
//   gemm2: R0 -> h2 split (R1, kills H0)
//   gemm3: R1 -> h3 fp32  (F32_R0, kills h1)
//   gather512: F32_R0 -> h4 split (R1, kills h2)
//   gemm4: R1 -> h5 split (R0, kills h3)
//   gemm5: R0 -> h6 split (R1, kills h4)
//   gemm6: R1 -> h7 fp32  (F32_R0, kills h5)
//   fc2:   F32_R0 -> out
// ---------------------------------------------------------------------------
extern "C" void kernel_launch(void* const* d_in, const int* in_sizes, int n_in,
                              void* d_out, int out_size, void* d_ws, size_t ws_size,
                              hipStream_t stream) {
    const float* x      = (const float*)d_in[0];
    const int*   ei     = (const int*)d_in[1];
    const int*   teid   = (const int*)d_in[2];
    const float* W1     = (const float*)d_in[3];
    const float* b1     = (const float*)d_in[4];
    const float* W2     = (const float*)d_in[5];
    const float* b2     = (const float*)d_in[6];
    const float* W3     = (const float*)d_in[7];
    const float* b3     = (const float*)d_in[8];
    const float* bn1_g  = (const float*)d_in[9];
    const float* bn1_b  = (const float*)d_in[10];
    const float* bn1_m  = (const float*)d_in[11];
    const float* bn1_v  = (const float*)d_in[12];
    const float* eps1   = (const float*)d_in[13];
    const float* W4     = (const float*)d_in[14];
    const float* b4     = (const float*)d_in[15];
    const float* bn2_g  = (const float*)d_in[16];
    const float* bn2_b  = (const float*)d_in[17];
    const float* bn2_m  = (const float*)d_in[18];
    const float* bn2_v  = (const float*)d_in[19];
    const float* eps2   = (const float*)d_in[20];
    const float* lin1_W = (const float*)d_in[21];
    const float* lin1_b = (const float*)d_in[22];
    const float* lin2_W = (const float*)d_in[23];
    const float* lin2_b = (const float*)d_in[24];
    const float* fc2_W  = (const float*)d_in[25];
    const float* fc2_b  = (const float*)d_in[26];

    const size_t PLANE   = (size_t)MPAD * HIDDEN;
    const size_t PLANE64 = (size_t)MPAD * IN_F;

    ushort_t* R0h = (ushort_t*)d_ws;
    ushort_t* R0l = R0h + PLANE;
    ushort_t* R1h = R0l + PLANE;
    ushort_t* R1l = R1h + PLANE;

    const size_t WSMALL = (size_t)HIDDEN * IN_F;
    const size_t WBIG   = (size_t)HIDDEN * HIDDEN;
    ushort_t* Wp   = R1l + PLANE;
    ushort_t* Wt1h = Wp;            ushort_t* Wt1l = Wt1h + WSMALL;
    ushort_t* Wt2h = Wt1l + WSMALL; ushort_t* Wt2l = Wt2h + WBIG;
    ushort_t* Wt3h = Wt2l + WBIG;   ushort_t* Wt3l = Wt3h + WBIG;
    ushort_t* Wt4h = Wt3l + WBIG;   ushort_t* Wt4l = Wt4h + WBIG;
    ushort_t* Wt5h = Wt4l + WBIG;   ushort_t* Wt5l = Wt5h + WBIG;
    ushort_t* Wt6h = Wt5l + WBIG;   ushort_t* Wt6l = Wt6h + WBIG;

    // CSR arrays (ints) after weights
    int* deg    = (int*)(Wt6l + WBIG);   // also scatter cursor
    int* rowptr = deg + N_NODES;         // N_NODES + 1
    int* adj    = rowptr + (N_NODES + 1);

    // fp32 aliases
    float* F32_R0 = (float*)R0h;
    // H0 split planes at head of R1 region
    ushort_t* H0h = R1h;
    ushort_t* H0l = R1h + PLANE64;

    // ---- CSR build ----
    zero_kernel<<<(N_NODES + 255) / 256, 256, 0, stream>>>(deg, N_NODES);
    hist_kernel<<<(N_EDGES + 255) / 256, 256, 0, stream>>>(ei, deg);
    scan_kernel<<<1, 1024, 0, stream>>>(deg, rowptr);
    cursor_init_kernel<<<(N_NODES + 255) / 256, 256, 0, stream>>>(rowptr, deg);
    scatter_kernel<<<(N_EDGES + 255) / 256, 256, 0, stream>>>(ei, deg, adj);

    // ---- weight prep: transpose + split ----
    dim3 wtgS(HIDDEN / 32, IN_F / 32);
    dim3 wtgB(HIDDEN / 32, HIDDEN / 32);
    wtrans_kernel<<<wtgS, 256, 0, stream>>>(W1, Wt1h, Wt1l, IN_F);
    wtrans_kernel<<<wtgB, 256, 0, stream>>>(W2, Wt2h, Wt2l, HIDDEN);
    wtrans_kernel<<<wtgB, 256, 0, stream>>>(W3, Wt3h, Wt3l, HIDDEN);
    wtrans_kernel<<<wtgB, 256, 0, stream>>>(W4, Wt4h, Wt4l, HIDDEN);
    wtrans_kernel<<<wtgB, 256, 0, stream>>>(lin1_W, Wt5h, Wt5l, HIDDEN);
    wtrans_kernel<<<wtgB, 256, 0, stream>>>(lin2_W, Wt6h, Wt6l, HIDDEN);

    const int ngrid = MT * NT;     // 1564 blocks, 1-D swizzled grid
    int nwb = (N_NODES + 3) / 4;   // wave-per-node blocks (4 waves/block)

    // ---- h0 = (1+eps1)*x + gather(x) -> H0 split ----
    gather64_kernel<<<nwb, 256, 0, stream>>>(x, rowptr, adj, eps1, H0h, H0l);

    // h1 = relu(h0 @ W1 + b1) -> R0 split
    gemm_direct_kernel<IN_F><<<ngrid, 256, 0, stream>>>(H0h, H0l, Wt1h, Wt1l, b1,
        nullptr, R0h, R0l, 1, nullptr, nullptr, nullptr, nullptr);
    // h2 = relu(h1 @ W2 + b2) -> R1 split
    gemm_direct_kernel<HIDDEN><<<ngrid, 256, 0, stream>>>(R0h, R0l, Wt2h, Wt2l, b2,
        nullptr, R1h, R1l, 1, nullptr, nullptr, nullptr, nullptr);
    // h3 = bn1(relu(h2 @ W3 + b3)) -> F32_R0
    gemm_direct_kernel<HIDDEN><<<ngrid, 256, 0, stream>>>(R1h, R1l, Wt3h, Wt3l, b3,
        F32_R0, nullptr, nullptr, 2, bn1_g, bn1_b, bn1_m, bn1_v);

    // ---- h4 = (1+eps2)*h3 + gather(h3) -> R1 split ----
    gather512_kernel<<<nwb, 256, 0, stream>>>(F32_R0, rowptr, adj, eps2, R1h, R1l);

    // h5 = bn2(relu(h4 @ W4 + b4)) -> R0 split
    gemm_direct_kernel<HIDDEN><<<ngrid, 256, 0, stream>>>(R1h, R1l, Wt4h, Wt4l, b4,
        nullptr, R0h, R0l, 2, bn2_g, bn2_b, bn2_m, bn2_v);
    // h6 = relu(h5 @ lin1_W + lin1_b) -> R1 split
    gemm_direct_kernel<HIDDEN><<<ngrid, 256, 0, stream>>>(R0h, R0l, Wt5h, Wt5l, lin1_b,
        nullptr, R1h, R1l, 1, nullptr, nullptr, nullptr, nullptr);
    // h7 = h6 @ lin2_W + lin2_b -> F32_R0
    gemm_direct_kernel<HIDDEN><<<ngrid, 256, 0, stream>>>(R1h, R1l, Wt6h, Wt6l, lin2_b,
        F32_R0, nullptr, nullptr, 0, nullptr, nullptr, nullptr, nullptr);

    // head
    fc2_kernel<<<(N_TRAIN + 3) / 4, 256, 0, stream>>>(F32_R0, ei, teid, fc2_W, fc2_b,
                                                      (float*)d_out);
}

// Round 7
// 1101.677 us; speedup vs baseline: 1.4882x; 1.4882x over previous
//
#include <hip/hip_runtime.h>

#define N_NODES 50000
#define MPAD    50048           // N_NODES rounded up to 128
#define IN_F    64
#define HIDDEN  512
#define N_EDGES 160000
#define N_TRAIN 80000
#define N_CLASS 7
#define BN_EPS  1e-5f

#define MT      (MPAD / 128)    // 391 m-tiles
#define NT      4               // 128-col n-tiles
#define FULLGRP ((MT / 8) * 32) // 1536: full 8-mtile x 4-ntile swizzle groups

typedef short  bf16x8 __attribute__((ext_vector_type(8)));
typedef float  f32x4  __attribute__((ext_vector_type(4)));
typedef unsigned short ushort_t;

// ---- bf16 helpers (manual RNE; values are finite) -------------------------
__device__ __forceinline__ ushort_t f2b(float v) {
    union { float f; unsigned int u; } c; c.f = v;
    unsigned int x = c.u;
    unsigned int r = (x + 0x7FFFu + ((x >> 16) & 1u)) >> 16;
    return (ushort_t)r;
}
__device__ __forceinline__ float b2f(ushort_t b) {
    union { unsigned int u; float f; } c; c.u = ((unsigned int)b) << 16;
    return c.f;
}

// ---- async global->LDS, 16B per lane (dst = wave-uniform base + lane*16) --
__device__ __forceinline__ void async_copy16(const void* g, void* l) {
    __builtin_amdgcn_global_load_lds(
        (const __attribute__((address_space(1))) void*)g,
        (__attribute__((address_space(3))) void*)l, 16, 0, 0);
}

// ===========================================================================
// CSR build: zero -> histogram(dst) -> exclusive scan -> scatter src ids
// ===========================================================================
__global__ void zero_kernel(int* __restrict__ p, int n) {
    int i = blockIdx.x * blockDim.x + threadIdx.x;
    if (i < n) p[i] = 0;
}

__global__ void hist_kernel(const int* __restrict__ ei, int* __restrict__ deg) {
    int e = blockIdx.x * blockDim.x + threadIdx.x;
    if (e >= N_EDGES) return;
    atomicAdd(&deg[ei[N_EDGES + e]], 1);
}

// single block, 1024 threads; rowptr[0]=0, rowptr[i+1]=incl_scan(deg)[i]
__global__ __launch_bounds__(1024) void scan_kernel(const int* __restrict__ deg,
                                                    int* __restrict__ rowptr) {
    __shared__ int buf[1024];
    __shared__ int carry_s;
    int tid = threadIdx.x;
    if (tid == 0) { carry_s = 0; rowptr[0] = 0; }
    __syncthreads();
    for (int base = 0; base < N_NODES; base += 1024) {
        int i = base + tid;
        buf[tid] = (i < N_NODES) ? deg[i] : 0;
        __syncthreads();
        for (int off = 1; off < 1024; off <<= 1) {
            int t = (tid >= off) ? buf[tid - off] : 0;
            __syncthreads();
            buf[tid] += t;
            __syncthreads();
        }
        if (i < N_NODES) rowptr[i + 1] = buf[tid] + carry_s;
        __syncthreads();
        if (tid == 0) carry_s += buf[1023];
        __syncthreads();
    }
}

__global__ void cursor_init_kernel(const int* __restrict__ rowptr,
                                   int* __restrict__ cursor) {
    int i = blockIdx.x * blockDim.x + threadIdx.x;
    if (i < N_NODES) cursor[i] = rowptr[i];
}

__global__ void scatter_kernel(const int* __restrict__ ei,
                               int* __restrict__ cursor, int* __restrict__ adj) {
    int e = blockIdx.x * blockDim.x + threadIdx.x;
    if (e >= N_EDGES) return;
    int src = ei[e], dst = ei[N_EDGES + e];
    int pos = atomicAdd(&cursor[dst], 1);
    adj[pos] = src;
}

// ===========================================================================
// Gather aggregation (CSR), fused scale + split-bf16 output.
// out[n] = (1+eps)*h[n] + sum_{k in row n} h[adj[k]]
// ===========================================================================
__global__ __launch_bounds__(256) void gather64_kernel(
    const float* __restrict__ x, const int* __restrict__ rowptr,
    const int* __restrict__ adj, const float* __restrict__ epsp,
    ushort_t* __restrict__ hi, ushort_t* __restrict__ lo) {
    int wave = threadIdx.x >> 6, lane = threadIdx.x & 63;
    int n = blockIdx.x * 4 + wave;
    if (n >= N_NODES) return;
    float s = 1.0f + *epsp;
    float sum = s * x[(size_t)n * IN_F + lane];
    int beg = rowptr[n], end = rowptr[n + 1];
    for (int k = beg; k < end; k++) {
        sum += x[(size_t)adj[k] * IN_F + lane];
    }
    ushort_t hb = f2b(sum);
    ushort_t lb = f2b(sum - b2f(hb));
    hi[(size_t)n * IN_F + lane] = hb;
    lo[(size_t)n * IN_F + lane] = lb;
}

__global__ __launch_bounds__(256) void gather512_kernel(
    const float* __restrict__ h, const int* __restrict__ rowptr,
    const int* __restrict__ adj, const float* __restrict__ epsp,
    ushort_t* __restrict__ hi, ushort_t* __restrict__ lo) {
    int wave = threadIdx.x >> 6, lane = threadIdx.x & 63;
    int n = blockIdx.x * 4 + wave;
    if (n >= N_NODES) return;
    float s = 1.0f + *epsp;
    const float* hn = h + (size_t)n * HIDDEN;
    const int f0 = lane * 4, f1 = 256 + lane * 4;
    float4 a0 = *(const float4*)&hn[f0];
    float4 a1 = *(const float4*)&hn[f1];
    float sum0[4] = {s * a0.x, s * a0.y, s * a0.z, s * a0.w};
    float sum1[4] = {s * a1.x, s * a1.y, s * a1.z, s * a1.w};
    int beg = rowptr[n], end = rowptr[n + 1];
    for (int k = beg; k < end; k++) {
        const float* hs = h + (size_t)adj[k] * HIDDEN;
        float4 b0 = *(const float4*)&hs[f0];
        float4 b1 = *(const float4*)&hs[f1];
        sum0[0] += b0.x; sum0[1] += b0.y; sum0[2] += b0.z; sum0[3] += b0.w;
        sum1[0] += b1.x; sum1[1] += b1.y; sum1[2] += b1.z; sum1[3] += b1.w;
    }
    ushort_t h4[4], l4[4];
#pragma unroll
    for (int j = 0; j < 4; j++) {
        h4[j] = f2b(sum0[j]);
        l4[j] = f2b(sum0[j] - b2f(h4[j]));
    }
    *(ushort4*)&hi[(size_t)n * HIDDEN + f0] = make_ushort4(h4[0], h4[1], h4[2], h4[3]);
    *(ushort4*)&lo[(size_t)n * HIDDEN + f0] = make_ushort4(l4[0], l4[1], l4[2], l4[3]);
#pragma unroll
    for (int j = 0; j < 4; j++) {
        h4[j] = f2b(sum1[j]);
        l4[j] = f2b(sum1[j] - b2f(h4[j]));
    }
    *(ushort4*)&hi[(size_t)n * HIDDEN + f1] = make_ushort4(h4[0], h4[1], h4[2], h4[3]);
    *(ushort4*)&lo[(size_t)n * HIDDEN + f1] = make_ushort4(l4[0], l4[1], l4[2], l4[3]);
}

// ---------------------------------------------------------------------------
// W[K][512] fp32 -> Wt_hi[512][K], Wt_lo[512][K] bf16 (transpose + split)
// ---------------------------------------------------------------------------
__global__ void wtrans_kernel(const float* __restrict__ W,
                              ushort_t* __restrict__ Whi,
                              ushort_t* __restrict__ Wlo, int K) {
    __shared__ float t[32][33];
    int tx = threadIdx.x & 31, ty = threadIdx.x >> 5;   // ty 0..7
    int nb = blockIdx.x * 32, kb = blockIdx.y * 32;
#pragma unroll
    for (int i = 0; i < 4; i++) {
        int k = kb + ty + i * 8;
        t[ty + i * 8][tx] = W[(size_t)k * HIDDEN + nb + tx];
    }
    __syncthreads();
#pragma unroll
    for (int i = 0; i < 4; i++) {
        int n = nb + ty + i * 8;
        int k = kb + tx;
        float v = t[tx][ty + i * 8];
        ushort_t hb = f2b(v);
        ushort_t lb = f2b(v - b2f(hb));
        Whi[(size_t)n * K + k] = hb;
        Wlo[(size_t)n * K + k] = lb;
    }
}

// ---------------------------------------------------------------------------
// Split-bf16 MFMA GEMM, double-buffered LDS, bank-conflict swizzle.
// C = epilogue(A @ B + bias), N = 512 fixed, K compile-time (64 or 512).
// 128x128 tile, BK=32, 256 threads (4 waves 2x2), 16x16x32 MFMA, 3-term split.
//
// K-loop: ONE barrier per iter; prefetch of tile k+1 is issued AFTER the
// barrier, so the vmcnt(0) drain at barrier i+1 waits on loads that aged a
// full compute phase (~0 stall), unlike the 2-barrier structure where the
// drain immediately follows issue.
//
// Swizzle: LDS row stride is 64 B (16 banks), so same-parity rows fully
// alias. Rotate each row's four 16-B k-chunks by ((row>>1)&3) — applied to
// the GLOBAL source offset (LDS dst of global_load_lds must stay
// base+lane*16). Fragment reads apply the inverse rotation. Result: each
// 4-bank group is hit by exactly 2 lanes (free, m136) instead of 8.
// ---------------------------------------------------------------------------
template<int K>
__global__ __launch_bounds__(256) void gemm_dbuf_kernel(
    const ushort_t* __restrict__ Ahi, const ushort_t* __restrict__ Alo,
    const ushort_t* __restrict__ Bhi, const ushort_t* __restrict__ Blo,
    const float* __restrict__ bias,
    float* __restrict__ Cf, ushort_t* __restrict__ Chi, ushort_t* __restrict__ Clo,
    int mode,
    const float* __restrict__ bn_g, const float* __restrict__ bn_b,
    const float* __restrict__ bn_m, const float* __restrict__ bn_v) {
    __shared__ ushort_t As_h[2][128 * 32];
    __shared__ ushort_t As_l[2][128 * 32];
    __shared__ ushort_t Bs_h[2][128 * 32];
    __shared__ ushort_t Bs_l[2][128 * 32];

    const int tid  = threadIdx.x;
    const int wave = tid >> 6, lane = tid & 63;
    const int wm = wave >> 1, wn = wave & 1;
    const int quad = lane >> 4, r = lane & 15;

    // XCD-aware tile mapping (blocks round-robin over 8 XCDs; each XCD runs
    // one m-tile's 4 n-tiles back-to-back so the A rows stay in its L2)
    int idx = blockIdx.x, m_t, n_t;
    if (idx < FULLGRP) {
        m_t = (idx >> 5) * 8 + (idx & 7);
        n_t = (idx >> 3) & 3;
    } else {
        int t = idx - FULLGRP;
        m_t = (FULLGRP >> 2) + (t >> 2);
        n_t = t & 3;
    }
    const int m0 = m_t * 128, n0 = n_t * 128;

    const f32x4 vzero = {0.f, 0.f, 0.f, 0.f};
    f32x4 acc[4][4];
#pragma unroll
    for (int i = 0; i < 4; i++)
#pragma unroll
        for (int j = 0; j < 4; j++) acc[i][j] = vzero;

    // staging geometry: lane (srow, c) lands at LDS row srow, chunk c;
    // source k-chunk is rotated by ((srow>>1)&3)
    const int srow = lane >> 2;                                  // 0..15
    const int scol = (((lane & 3) + ((srow >> 1) & 3)) & 3) * 8; // swizzled src chunk

    auto stage = [&](int buf, int k0) {
#pragma unroll
        for (int tt = 0; tt < 2; tt++) {
            int rr = wave * 32 + tt * 16 + srow;
            int lbase = (wave * 32 + tt * 16) * 32;
            size_t ga = (size_t)(m0 + rr) * K + k0 + scol;
            size_t gb = (size_t)(n0 + rr) * K + k0 + scol;
            async_copy16(Ahi + ga, &As_h[buf][lbase]);
            async_copy16(Alo + ga, &As_l[buf][lbase]);
            async_copy16(Bhi + gb, &Bs_h[buf][lbase]);
            async_copy16(Blo + gb, &Bs_l[buf][lbase]);
        }
    };

    // fragment read: inverse rotation; LDS row mod 16 == r for all tiles
    const int csw = ((quad - ((r >> 1) & 3)) & 3) * 8;

    stage(0, 0);
    for (int kk = 0; kk < K / 32; kk++) {
        const int cur = kk & 1;
        __syncthreads();                       // drain: buf[cur] loads landed
        if ((kk + 1) * 32 < K) stage(cur ^ 1, (kk + 1) * 32);

        bf16x8 ah[4], al[4], bh[4], bl[4];
#pragma unroll
        for (int i = 0; i < 4; i++) {
            int aofs = (wm * 64 + i * 16 + r) * 32 + csw;
            int bofs = (wn * 64 + i * 16 + r) * 32 + csw;
            ah[i] = *(const bf16x8*)&As_h[cur][aofs];
            al[i] = *(const bf16x8*)&As_l[cur][aofs];
            bh[i] = *(const bf16x8*)&Bs_h[cur][bofs];
            bl[i] = *(const bf16x8*)&Bs_l[cur][bofs];
        }
#pragma unroll
        for (int i = 0; i < 4; i++)
#pragma unroll
            for (int j = 0; j < 4; j++) {
                acc[i][j] = __builtin_amdgcn_mfma_f32_16x16x32_bf16(ah[i], bh[j], acc[i][j], 0, 0, 0);
                acc[i][j] = __builtin_amdgcn_mfma_f32_16x16x32_bf16(ah[i], bl[j], acc[i][j], 0, 0, 0);
                acc[i][j] = __builtin_amdgcn_mfma_f32_16x16x32_bf16(al[i], bh[j], acc[i][j], 0, 0, 0);
            }
    }

    // ---- epilogue ----
    float bia[4], sc[4], sh[4];
#pragma unroll
    for (int j = 0; j < 4; j++) {
        int col = n0 + wn * 64 + j * 16 + r;
        bia[j] = bias[col];
        if (mode == 2) {
            float g = bn_g[col], bb = bn_b[col], mm = bn_m[col], vv = bn_v[col];
            sc[j] = g * rsqrtf(vv + BN_EPS);
            sh[j] = bb - mm * sc[j];
        } else { sc[j] = 1.f; sh[j] = 0.f; }
    }
#pragma unroll
    for (int i = 0; i < 4; i++) {
#pragma unroll
        for (int rg = 0; rg < 4; rg++) {
            int row = m0 + wm * 64 + i * 16 + quad * 4 + rg;
            if (row >= N_NODES) continue;
#pragma unroll
            for (int j = 0; j < 4; j++) {
                int col = n0 + wn * 64 + j * 16 + r;
                float v = acc[i][j][rg] + bia[j];
                if (mode >= 1) v = fmaxf(v, 0.f);
                if (mode == 2) v = v * sc[j] + sh[j];
                size_t oix = (size_t)row * HIDDEN + col;
                if (Cf) {
                    Cf[oix] = v;
                } else {
                    ushort_t hb = f2b(v);
                    ushort_t lb = f2b(v - b2f(hb));
                    Chi[oix] = hb;
                    Clo[oix] = lb;
                }
            }
        }
    }
}

// ---------------------------------------------------------------------------
// out[t] = (h[a_t] * h[b_t]) @ fc2_W + fc2_b ; one wave per train edge.
// ---------------------------------------------------------------------------
__global__ __launch_bounds__(256) void fc2_kernel(
    const float* __restrict__ h, const int* __restrict__ ei,
    const int* __restrict__ teid, const float* __restrict__ W,
    const float* __restrict__ bias, float* __restrict__ out) {
    __shared__ float Ws[HIDDEN * N_CLASS];
    __shared__ float bs[N_CLASS];
    for (int i = threadIdx.x; i < HIDDEN * N_CLASS; i += blockDim.x) Ws[i] = W[i];
    if (threadIdx.x < N_CLASS) bs[threadIdx.x] = bias[threadIdx.x];
    __syncthreads();

    int wave = threadIdx.x >> 6;
    int lane = threadIdx.x & 63;
    int t = blockIdx.x * 4 + wave;
    if (t >= N_TRAIN) return;

    int e = teid[t];
    int a = ei[e];
    int b = ei[N_EDGES + e];
    const float* xa = h + (size_t)a * HIDDEN;
    const float* xb = h + (size_t)b * HIDDEN;

    float acc[N_CLASS];
#pragma unroll
    for (int c = 0; c < N_CLASS; c++) acc[c] = 0.f;

    int j0 = lane * 8;
    float4 a0 = *(const float4*)&xa[j0];
    float4 a1 = *(const float4*)&xa[j0 + 4];
    float4 b0 = *(const float4*)&xb[j0];
    float4 b1 = *(const float4*)&xb[j0 + 4];
    float p[8] = {a0.x * b0.x, a0.y * b0.y, a0.z * b0.z, a0.w * b0.w,
                  a1.x * b1.x, a1.y * b1.y, a1.z * b1.z, a1.w * b1.w};
#pragma unroll
    for (int jj = 0; jj < 8; jj++) {
        const float* wrow = &Ws[(j0 + jj) * N_CLASS];
#pragma unroll
        for (int c = 0; c < N_CLASS; c++) acc[c] = fmaf(p[jj], wrow[c], acc[c]);
    }
#pragma unroll
    for (int c = 0; c < N_CLASS; c++) {
        float v = acc[c];
        for (int off = 32; off > 0; off >>= 1) v += __shfl_down(v, off, 64);
        if (lane == 0) out[(size_t)t * N_CLASS + c] = v + bs[c];
    }
}

// ---------------------------------------------------------------------------
// Workspace (~211.4 MB):
//   R0h R0l R1h R1l (4 bf16 planes) | weights | CSR {deg/cursor, rowptr, adj}
// Liveness chain:
//   gather64 -> H0 split (head of R1)          [x input]
//   gemm1: H0 -> h1 split (R0)
//   gemm2: R0 -> h2 split (R1, kills H0)
//   gemm3: R1 -> h3 fp32  (F32_R0, kills h1)
//   gather512: F32_R0 -> h4 split (R1, kills h2)
//   gemm4: R1 -> h5 split (R0, kills h3)
//   gemm5: R0 -> h6 split (R1, kills h4)
//   gemm6: R1 -> h7 fp32  (F32_R0, kills h5)
//   fc2:   F32_R0 -> out
// ---------------------------------------------------------------------------
extern "C" void kernel_launch(void* const* d_in, const int* in_sizes, int n_in,
                              void* d_out, int out_size, void* d_ws, size_t ws_size,
                              hipStream_t stream) {
    const float* x      = (const float*)d_in[0];
    const int*   ei     = (const int*)d_in[1];
    const int*   teid   = (const int*)d_in[2];
    const float* W1     = (const float*)d_in[3];
    const float* b1     = (const float*)d_in[4];
    const float* W2     = (const float*)d_in[5];
    const float* b2     = (const float*)d_in[6];
    const float* W3     = (const float*)d_in[7];
    const float* b3     = (const float*)d_in[8];
    const float* bn1_g  = (const float*)d_in[9];
    const float* bn1_b  = (const float*)d_in[10];
    const float* bn1_m  = (const float*)d_in[11];
    const float* bn1_v  = (const float*)d_in[12];
    const float* eps1   = (const float*)d_in[13];
    const float* W4     = (const float*)d_in[14];
    const float* b4     = (const float*)d_in[15];
    const float* bn2_g  = (const float*)d_in[16];
    const float* bn2_b  = (const float*)d_in[17];
    const float* bn2_m  = (const float*)d_in[18];
    const float* bn2_v  = (const float*)d_in[19];
    const float* eps2   = (const float*)d_in[20];
    const float* lin1_W = (const float*)d_in[21];
    const float* lin1_b = (const float*)d_in[22];
    const float* lin2_W = (const float*)d_in[23];
    const float* lin2_b = (const float*)d_in[24];
    const float* fc2_W  = (const float*)d_in[25];
    const float* fc2_b  = (const float*)d_in[26];

    const size_t PLANE   = (size_t)MPAD * HIDDEN;
    const size_t PLANE64 = (size_t)MPAD * IN_F;

    ushort_t* R0h = (ushort_t*)d_ws;
    ushort_t* R0l = R0h + PLANE;
    ushort_t* R1h = R0l + PLANE;
    ushort_t* R1l = R1h + PLANE;

    const size_t WSMALL = (size_t)HIDDEN * IN_F;
    const size_t WBIG   = (size_t)HIDDEN * HIDDEN;
    ushort_t* Wp   = R1l + PLANE;
    ushort_t* Wt1h = Wp;            ushort_t* Wt1l = Wt1h + WSMALL;
    ushort_t* Wt2h = Wt1l + WSMALL; ushort_t* Wt2l = Wt2h + WBIG;
    ushort_t* Wt3h = Wt2l + WBIG;   ushort_t* Wt3l = Wt3h + WBIG;
    ushort_t* Wt4h = Wt3l + WBIG;   ushort_t* Wt4l = Wt4h + WBIG;
    ushort_t* Wt5h = Wt4l + WBIG;   ushort_t* Wt5l = Wt5h + WBIG;
    ushort_t* Wt6h = Wt5l + WBIG;   ushort_t* Wt6l = Wt6h + WBIG;

    // CSR arrays (ints) after weights
    int* deg    = (int*)(Wt6l + WBIG);   // also scatter cursor
    int* rowptr = deg + N_NODES;         // N_NODES + 1
    int* adj    = rowptr + (N_NODES + 1);

    // fp32 aliases
    float* F32_R0 = (float*)R0h;
    // H0 split planes at head of R1 region
    ushort_t* H0h = R1h;
    ushort_t* H0l = R1h + PLANE64;

    // ---- CSR build ----
    zero_kernel<<<(N_NODES + 255) / 256, 256, 0, stream>>>(deg, N_NODES);
    hist_kernel<<<(N_EDGES + 255) / 256, 256, 0, stream>>>(ei, deg);
    scan_kernel<<<1, 1024, 0, stream>>>(deg, rowptr);
    cursor_init_kernel<<<(N_NODES + 255) / 256, 256, 0, stream>>>(rowptr, deg);
    scatter_kernel<<<(N_EDGES + 255) / 256, 256, 0, stream>>>(ei, deg, adj);

    // ---- weight prep: transpose + split ----
    dim3 wtgS(HIDDEN / 32, IN_F / 32);
    dim3 wtgB(HIDDEN / 32, HIDDEN / 32);
    wtrans_kernel<<<wtgS, 256, 0, stream>>>(W1, Wt1h, Wt1l, IN_F);
    wtrans_kernel<<<wtgB, 256, 0, stream>>>(W2, Wt2h, Wt2l, HIDDEN);
    wtrans_kernel<<<wtgB, 256, 0, stream>>>(W3, Wt3h, Wt3l, HIDDEN);
    wtrans_kernel<<<wtgB, 256, 0, stream>>>(W4, Wt4h, Wt4l, HIDDEN);
    wtrans_kernel<<<wtgB, 256, 0, stream>>>(lin1_W, Wt5h, Wt5l, HIDDEN);
    wtrans_kernel<<<wtgB, 256, 0, stream>>>(lin2_W, Wt6h, Wt6l, HIDDEN);

    const int ngrid = MT * NT;     // 1564 blocks, 1-D swizzled grid
    int nwb = (N_NODES + 3) / 4;   // wave-per-node blocks (4 waves/block)

    // ---- h0 = (1+eps1)*x + gather(x) -> H0 split ----
    gather64_kernel<<<nwb, 256, 0, stream>>>(x, rowptr, adj, eps1, H0h, H0l);

    // h1 = relu(h0 @ W1 + b1) -> R0 split
    gemm_dbuf_kernel<IN_F><<<ngrid, 256, 0, stream>>>(H0h, H0l, Wt1h, Wt1l, b1,
        nullptr, R0h, R0l, 1, nullptr, nullptr, nullptr, nullptr);
    // h2 = relu(h1 @ W2 + b2) -> R1 split
    gemm_dbuf_kernel<HIDDEN><<<ngrid, 256, 0, stream>>>(R0h, R0l, Wt2h, Wt2l, b2,
        nullptr, R1h, R1l, 1, nullptr, nullptr, nullptr, nullptr);
    // h3 = bn1(relu(h2 @ W3 + b3)) -> F32_R0
    gemm_dbuf_kernel<HIDDEN><<<ngrid, 256, 0, stream>>>(R1h, R1l, Wt3h, Wt3l, b3,
        F32_R0, nullptr, nullptr, 2, bn1_g, bn1_b, bn1_m, bn1_v);

    // ---- h4 = (1+eps2)*h3 + gather(h3) -> R1 split ----
    gather512_kernel<<<nwb, 256, 0, stream>>>(F32_R0, rowptr, adj, eps2, R1h, R1l);

    // h5 = bn2(relu(h4 @ W4 + b4)) -> R0 split
    gemm_dbuf_kernel<HIDDEN><<<ngrid, 256, 0, stream>>>(R1h, R1l, Wt4h, Wt4l, b4,
        nullptr, R0h, R0l, 2, bn2_g, bn2_b, bn2_m, bn2_v);
    // h6 = relu(h5 @ lin1_W + lin1_b) -> R1 split
    gemm_dbuf_kernel<HIDDEN><<<ngrid, 256, 0, stream>>>(R0h, R0l, Wt5h, Wt5l, lin1_b,
        nullptr, R1h, R1l, 1, nullptr, nullptr, nullptr, nullptr);
    // h7 = h6 @ lin2_W + lin2_b -> F32_R0
    gemm_dbuf_kernel<HIDDEN><<<ngrid, 256, 0, stream>>>(R1h, R1l, Wt6h, Wt6l, lin2_b,
        F32_R0, nullptr, nullptr, 0, nullptr, nullptr, nullptr, nullptr);

    // head
    fc2_kernel<<<(N_TRAIN + 3) / 4, 256, 0, stream>>>(F32_R0, ei, teid, fc2_W, fc2_b,
                                                      (float*)d_out);
}

// Round 8
// 1036.350 us; speedup vs baseline: 1.5820x; 1.0630x over previous
//
#include <hip/hip_runtime.h>

#define N_NODES 50000
#define MPAD    50048           // N_NODES rounded up to 128
#define IN_F    64
#define HIDDEN  512
#define N_EDGES 160000
#define N_TRAIN 80000
#define N_CLASS 7
#define BN_EPS  1e-5f

#define MT      (MPAD / 128)    // 391 m-tiles
#define NT      4               // 128-col n-tiles
#define FULLGRP ((MT / 8) * 32) // 1536: full 8-mtile x 4-ntile swizzle groups

typedef short  bf16x8 __attribute__((ext_vector_type(8)));
typedef float  f32x4  __attribute__((ext_vector_type(4)));
typedef unsigned short ushort_t;

// ---- bf16 helpers (manual RNE; values are finite) -------------------------
__device__ __forceinline__ ushort_t f2b(float v) {
    union { float f; unsigned int u; } c; c.f = v;
    unsigned int x = c.u;
    unsigned int r = (x + 0x7FFFu + ((x >> 16) & 1u)) >> 16;
    return (ushort_t)r;
}
__device__ __forceinline__ float b2f(ushort_t b) {
    union { unsigned int u; float f; } c; c.u = ((unsigned int)b) << 16;
    return c.f;
}

// ---- async global->LDS, 16B per lane (dst = wave-uniform base + lane*16) --
__device__ __forceinline__ void async_copy16(const void* g, void* l) {
    __builtin_amdgcn_global_load_lds(
        (const __attribute__((address_space(1))) void*)g,
        (__attribute__((address_space(3))) void*)l, 16, 0, 0);
}

// ===========================================================================
// CSR build: zero -> histogram(dst) -> exclusive scan -> scatter src ids
// ===========================================================================
__global__ void zero_kernel(int* __restrict__ p, int n) {
    int i = blockIdx.x * blockDim.x + threadIdx.x;
    if (i < n) p[i] = 0;
}

__global__ void hist_kernel(const int* __restrict__ ei, int* __restrict__ deg) {
    int e = blockIdx.x * blockDim.x + threadIdx.x;
    if (e >= N_EDGES) return;
    atomicAdd(&deg[ei[N_EDGES + e]], 1);
}

// single block, 1024 threads; rowptr[0]=0, rowptr[i+1]=incl_scan(deg)[i]
__global__ __launch_bounds__(1024) void scan_kernel(const int* __restrict__ deg,
                                                    int* __restrict__ rowptr) {
    __shared__ int buf[1024];
    __shared__ int carry_s;
    int tid = threadIdx.x;
    if (tid == 0) { carry_s = 0; rowptr[0] = 0; }
    __syncthreads();
    for (int base = 0; base < N_NODES; base += 1024) {
        int i = base + tid;
        buf[tid] = (i < N_NODES) ? deg[i] : 0;
        __syncthreads();
        for (int off = 1; off < 1024; off <<= 1) {
            int t = (tid >= off) ? buf[tid - off] : 0;
            __syncthreads();
            buf[tid] += t;
            __syncthreads();
        }
        if (i < N_NODES) rowptr[i + 1] = buf[tid] + carry_s;
        __syncthreads();
        if (tid == 0) carry_s += buf[1023];
        __syncthreads();
    }
}

__global__ void cursor_init_kernel(const int* __restrict__ rowptr,
                                   int* __restrict__ cursor) {
    int i = blockIdx.x * blockDim.x + threadIdx.x;
    if (i < N_NODES) cursor[i] = rowptr[i];
}

__global__ void scatter_kernel(const int* __restrict__ ei,
                               int* __restrict__ cursor, int* __restrict__ adj) {
    int e = blockIdx.x * blockDim.x + threadIdx.x;
    if (e >= N_EDGES) return;
    int src = ei[e], dst = ei[N_EDGES + e];
    int pos = atomicAdd(&cursor[dst], 1);
    adj[pos] = src;
}

// ===========================================================================
// Gather aggregation (CSR), fused scale + split-bf16 output.
// out[n] = (1+eps)*h[n] + sum_{k in row n} h[adj[k]]
// ===========================================================================
__global__ __launch_bounds__(256) void gather64_kernel(
    const float* __restrict__ x, const int* __restrict__ rowptr,
    const int* __restrict__ adj, const float* __restrict__ epsp,
    ushort_t* __restrict__ hi, ushort_t* __restrict__ lo) {
    int wave = threadIdx.x >> 6, lane = threadIdx.x & 63;
    int n = blockIdx.x * 4 + wave;
    if (n >= N_NODES) return;
    float s = 1.0f + *epsp;
    float sum = s * x[(size_t)n * IN_F + lane];
    int beg = rowptr[n], end = rowptr[n + 1];
    for (int k = beg; k < end; k++) {
        sum += x[(size_t)adj[k] * IN_F + lane];
    }
    ushort_t hb = f2b(sum);
    ushort_t lb = f2b(sum - b2f(hb));
    hi[(size_t)n * IN_F + lane] = hb;
    lo[(size_t)n * IN_F + lane] = lb;
}

// 2 waves per node (256 features each): halves the dependent-load chain per
// wave vs 1-wave/node and doubles wave-level parallelism for latency hiding.
__global__ __launch_bounds__(256) void gather512_kernel(
    const float* __restrict__ h, const int* __restrict__ rowptr,
    const int* __restrict__ adj, const float* __restrict__ epsp,
    ushort_t* __restrict__ hi, ushort_t* __restrict__ lo) {
    int wave = threadIdx.x >> 6, lane = threadIdx.x & 63;
    int n = blockIdx.x * 2 + (wave >> 1);
    if (n >= N_NODES) return;
    float s = 1.0f + *epsp;
    const int f = (wave & 1) * 256 + lane * 4;
    float4 a = *(const float4*)&h[(size_t)n * HIDDEN + f];
    float sum[4] = {s * a.x, s * a.y, s * a.z, s * a.w};
    int beg = rowptr[n], end = rowptr[n + 1];
    for (int k = beg; k < end; k++) {
        float4 b = *(const float4*)&h[(size_t)adj[k] * HIDDEN + f];
        sum[0] += b.x; sum[1] += b.y; sum[2] += b.z; sum[3] += b.w;
    }
    ushort_t h4[4], l4[4];
#pragma unroll
    for (int j = 0; j < 4; j++) {
        h4[j] = f2b(sum[j]);
        l4[j] = f2b(sum[j] - b2f(h4[j]));
    }
    *(ushort4*)&hi[(size_t)n * HIDDEN + f] = make_ushort4(h4[0], h4[1], h4[2], h4[3]);
    *(ushort4*)&lo[(size_t)n * HIDDEN + f] = make_ushort4(l4[0], l4[1], l4[2], l4[3]);
}

// ---------------------------------------------------------------------------
// W[K][512] fp32 -> Wt_hi[512][K], Wt_lo[512][K] bf16 (transpose + split)
// ---------------------------------------------------------------------------
__global__ void wtrans_kernel(const float* __restrict__ W,
                              ushort_t* __restrict__ Whi,
                              ushort_t* __restrict__ Wlo, int K) {
    __shared__ float t[32][33];
    int tx = threadIdx.x & 31, ty = threadIdx.x >> 5;   // ty 0..7
    int nb = blockIdx.x * 32, kb = blockIdx.y * 32;
#pragma unroll
    for (int i = 0; i < 4; i++) {
        int k = kb + ty + i * 8;
        t[ty + i * 8][tx] = W[(size_t)k * HIDDEN + nb + tx];
    }
    __syncthreads();
#pragma unroll
    for (int i = 0; i < 4; i++) {
        int n = nb + ty + i * 8;
        int k = kb + tx;
        float v = t[tx][ty + i * 8];
        ushort_t hb = f2b(v);
        ushort_t lb = f2b(v - b2f(hb));
        Whi[(size_t)n * K + k] = hb;
        Wlo[(size_t)n * K + k] = lb;
    }
}

// ---------------------------------------------------------------------------
// Split-bf16 MFMA GEMM: single-buffer LDS (32 KB, ~5 blocks/CU) + verified
// bank-conflict swizzle (R7: conflicts 6.4M -> 0). 128x128 tile, BK=32,
// 256 threads (4 waves 2x2), 16x16x32 MFMA, 3-term split accumulate.
// R6 (no-LDS) and R7 (64KB dbuf) both regressed; this is the best-measured
// structure. mode 0 none, 1 relu, 2 relu+bn.
//
// Swizzle: LDS row stride is 64 B (16 banks); rotate each row's four 16-B
// k-chunks by ((row>>1)&3), applied to the GLOBAL source offset (LDS dst of
// global_load_lds must stay base+lane*16). Fragment reads invert it.
// ---------------------------------------------------------------------------
template<int K>
__global__ __launch_bounds__(256) void gemm_split_kernel(
    const ushort_t* __restrict__ Ahi, const ushort_t* __restrict__ Alo,
    const ushort_t* __restrict__ Bhi, const ushort_t* __restrict__ Blo,
    const float* __restrict__ bias,
    float* __restrict__ Cf, ushort_t* __restrict__ Chi, ushort_t* __restrict__ Clo,
    int mode,
    const float* __restrict__ bn_g, const float* __restrict__ bn_b,
    const float* __restrict__ bn_m, const float* __restrict__ bn_v) {
    __shared__ ushort_t As_h[128 * 32];
    __shared__ ushort_t As_l[128 * 32];
    __shared__ ushort_t Bs_h[128 * 32];
    __shared__ ushort_t Bs_l[128 * 32];

    const int tid  = threadIdx.x;
    const int wave = tid >> 6, lane = tid & 63;
    const int wm = wave >> 1, wn = wave & 1;
    const int quad = lane >> 4, r = lane & 15;

    // XCD-aware tile mapping (blocks round-robin over 8 XCDs; each XCD runs
    // one m-tile's 4 n-tiles back-to-back so the A rows stay in its L2)
    int idx = blockIdx.x, m_t, n_t;
    if (idx < FULLGRP) {
        m_t = (idx >> 5) * 8 + (idx & 7);
        n_t = (idx >> 3) & 3;
    } else {
        int t = idx - FULLGRP;
        m_t = (FULLGRP >> 2) + (t >> 2);
        n_t = t & 3;
    }
    const int m0 = m_t * 128, n0 = n_t * 128;

    const f32x4 vzero = {0.f, 0.f, 0.f, 0.f};
    f32x4 acc[4][4];
#pragma unroll
    for (int i = 0; i < 4; i++)
#pragma unroll
        for (int j = 0; j < 4; j++) acc[i][j] = vzero;

    // staging geometry (swizzled source chunk)
    const int srow = lane >> 2;                                  // 0..15
    const int scol = (((lane & 3) + ((srow >> 1) & 3)) & 3) * 8; // swizzled src chunk
    // fragment read: inverse rotation (row mod 16 == r)
    const int csw  = ((quad - ((r >> 1) & 3)) & 3) * 8;

    for (int k0 = 0; k0 < K; k0 += 32) {
        __syncthreads();
#pragma unroll
        for (int tt = 0; tt < 2; tt++) {
            int rr = wave * 32 + tt * 16 + srow;
            int lbase = (wave * 32 + tt * 16) * 32;
            size_t ga = (size_t)(m0 + rr) * K + k0 + scol;
            size_t gb = (size_t)(n0 + rr) * K + k0 + scol;
            async_copy16(Ahi + ga, &As_h[lbase]);
            async_copy16(Alo + ga, &As_l[lbase]);
            async_copy16(Bhi + gb, &Bs_h[lbase]);
            async_copy16(Blo + gb, &Bs_l[lbase]);
        }
        __syncthreads();

        bf16x8 ah[4], al[4], bh[4], bl[4];
#pragma unroll
        for (int i = 0; i < 4; i++) {
            int aofs = (wm * 64 + i * 16 + r) * 32 + csw;
            int bofs = (wn * 64 + i * 16 + r) * 32 + csw;
            ah[i] = *(const bf16x8*)&As_h[aofs];
            al[i] = *(const bf16x8*)&As_l[aofs];
            bh[i] = *(const bf16x8*)&Bs_h[bofs];
            bl[i] = *(const bf16x8*)&Bs_l[bofs];
        }
#pragma unroll
        for (int i = 0; i < 4; i++)
#pragma unroll
            for (int j = 0; j < 4; j++) {
                acc[i][j] = __builtin_amdgcn_mfma_f32_16x16x32_bf16(ah[i], bh[j], acc[i][j], 0, 0, 0);
                acc[i][j] = __builtin_amdgcn_mfma_f32_16x16x32_bf16(ah[i], bl[j], acc[i][j], 0, 0, 0);
                acc[i][j] = __builtin_amdgcn_mfma_f32_16x16x32_bf16(al[i], bh[j], acc[i][j], 0, 0, 0);
            }
    }

    // ---- epilogue ----
    float bia[4], sc[4], sh[4];
#pragma unroll
    for (int j = 0; j < 4; j++) {
        int col = n0 + wn * 64 + j * 16 + r;
        bia[j] = bias[col];
        if (mode == 2) {
            float g = bn_g[col], bb = bn_b[col], mm = bn_m[col], vv = bn_v[col];
            sc[j] = g * rsqrtf(vv + BN_EPS);
            sh[j] = bb - mm * sc[j];
        } else { sc[j] = 1.f; sh[j] = 0.f; }
    }
#pragma unroll
    for (int i = 0; i < 4; i++) {
#pragma unroll
        for (int rg = 0; rg < 4; rg++) {
            int row = m0 + wm * 64 + i * 16 + quad * 4 + rg;
            if (row >= N_NODES) continue;
#pragma unroll
            for (int j = 0; j < 4; j++) {
                int col = n0 + wn * 64 + j * 16 + r;
                float v = acc[i][j][rg] + bia[j];
                if (mode >= 1) v = fmaxf(v, 0.f);
                if (mode == 2) v = v * sc[j] + sh[j];
                size_t oix = (size_t)row * HIDDEN + col;
                if (Cf) {
                    Cf[oix] = v;
                } else {
                    ushort_t hb = f2b(v);
                    ushort_t lb = f2b(v - b2f(hb));
                    Chi[oix] = hb;
                    Clo[oix] = lb;
                }
            }
        }
    }
}

// ---------------------------------------------------------------------------
// out[t] = (h[a_t] * h[b_t]) @ fc2_W + fc2_b ; one wave per train edge.
// ---------------------------------------------------------------------------
__global__ __launch_bounds__(256) void fc2_kernel(
    const float* __restrict__ h, const int* __restrict__ ei,
    const int* __restrict__ teid, const float* __restrict__ W,
    const float* __restrict__ bias, float* __restrict__ out) {
    __shared__ float Ws[HIDDEN * N_CLASS];
    __shared__ float bs[N_CLASS];
    for (int i = threadIdx.x; i < HIDDEN * N_CLASS; i += blockDim.x) Ws[i] = W[i];
    if (threadIdx.x < N_CLASS) bs[threadIdx.x] = bias[threadIdx.x];
    __syncthreads();

    int wave = threadIdx.x >> 6;
    int lane = threadIdx.x & 63;
    int t = blockIdx.x * 4 + wave;
    if (t >= N_TRAIN) return;

    int e = teid[t];
    int a = ei[e];
    int b = ei[N_EDGES + e];
    const float* xa = h + (size_t)a * HIDDEN;
    const float* xb = h + (size_t)b * HIDDEN;

    float acc[N_CLASS];
#pragma unroll
    for (int c = 0; c < N_CLASS; c++) acc[c] = 0.f;

    int j0 = lane * 8;
    float4 a0 = *(const float4*)&xa[j0];
    float4 a1 = *(const float4*)&xa[j0 + 4];
    float4 b0 = *(const float4*)&xb[j0];
    float4 b1 = *(const float4*)&xb[j0 + 4];
    float p[8] = {a0.x * b0.x, a0.y * b0.y, a0.z * b0.z, a0.w * b0.w,
                  a1.x * b1.x, a1.y * b1.y, a1.z * b1.z, a1.w * b1.w};
#pragma unroll
    for (int jj = 0; jj < 8; jj++) {
        const float* wrow = &Ws[(j0 + jj) * N_CLASS];
#pragma unroll
        for (int c = 0; c < N_CLASS; c++) acc[c] = fmaf(p[jj], wrow[c], acc[c]);
    }
#pragma unroll
    for (int c = 0; c < N_CLASS; c++) {
        float v = acc[c];
        for (int off = 32; off > 0; off >>= 1) v += __shfl_down(v, off, 64);
        if (lane == 0) out[(size_t)t * N_CLASS + c] = v + bs[c];
    }
}

// ---------------------------------------------------------------------------
// Workspace (~211.4 MB):
//   R0h R0l R1h R1l (4 bf16 planes) | weights | CSR {deg/cursor, rowptr, adj}
// Liveness chain:
//   gather64 -> H0 split (head of R1)          [x input]
//   gemm1: H0 -> h1 split (R0)
//   gemm2: R0 -> h2 split (R1, kills H0)
//   gemm3: R1 -> h3 fp32  (F32_R0, kills h1)
//   gather512: F32_R0 -> h4 split (R1, kills h2)
//   gemm4: R1 -> h5 split (R0, kills h3)
//   gemm5: R0 -> h6 split (R1, kills h4)
//   gemm6: R1 -> h7 fp32  (F32_R0, kills h5)
//   fc2:   F32_R0 -> out
// ---------------------------------------------------------------------------
extern "C" void kernel_launch(void* const* d_in, const int* in_sizes, int n_in,
                              void* d_out, int out_size, void* d_ws, size_t ws_size,
                              hipStream_t stream) {
    const float* x      = (const float*)d_in[0];
    const int*   ei     = (const int*)d_in[1];
    const int*   teid   = (const int*)d_in[2];
    const float* W1     = (const float*)d_in[3];
    const float* b1     = (const float*)d_in[4];
    const float* W2     = (const float*)d_in[5];
    const float* b2     = (const float*)d_in[6];
    const float* W3     = (const float*)d_in[7];
    const float* b3     = (const float*)d_in[8];
    const float* bn1_g  = (const float*)d_in[9];
    const float* bn1_b  = (const float*)d_in[10];
    const float* bn1_m  = (const float*)d_in[11];
    const float* bn1_v  = (const float*)d_in[12];
    const float* eps1   = (const float*)d_in[13];
    const float* W4     = (const float*)d_in[14];
    const float* b4     = (const float*)d_in[15];
    const float* bn2_g  = (const float*)d_in[16];
    const float* bn2_b  = (const float*)d_in[17];
    const float* bn2_m  = (const float*)d_in[18];
    const float* bn2_v  = (const float*)d_in[19];
    const float* eps2   = (const float*)d_in[20];
    const float* lin1_W = (const float*)d_in[21];
    const float* lin1_b = (const float*)d_in[22];
    const float* lin2_W = (const float*)d_in[23];
    const float* lin2_b = (const float*)d_in[24];
    const float* fc2_W  = (const float*)d_in[25];
    const float* fc2_b  = (const float*)d_in[26];

    const size_t PLANE   = (size_t)MPAD * HIDDEN;
    const size_t PLANE64 = (size_t)MPAD * IN_F;

    ushort_t* R0h = (ushort_t*)d_ws;
    ushort_t* R0l = R0h + PLANE;
    ushort_t* R1h = R0l + PLANE;
    ushort_t* R1l = R1h + PLANE;

    const size_t WSMALL = (size_t)HIDDEN * IN_F;
    const size_t WBIG   = (size_t)HIDDEN * HIDDEN;
    ushort_t* Wp   = R1l + PLANE;
    ushort_t* Wt1h = Wp;            ushort_t* Wt1l = Wt1h + WSMALL;
    ushort_t* Wt2h = Wt1l + WSMALL; ushort_t* Wt2l = Wt2h + WBIG;
    ushort_t* Wt3h = Wt2l + WBIG;   ushort_t* Wt3l = Wt3h + WBIG;
    ushort_t* Wt4h = Wt3l + WBIG;   ushort_t* Wt4l = Wt4h + WBIG;
    ushort_t* Wt5h = Wt4l + WBIG;   ushort_t* Wt5l = Wt5h + WBIG;
    ushort_t* Wt6h = Wt5l + WBIG;   ushort_t* Wt6l = Wt6h + WBIG;

    // CSR arrays (ints) after weights
    int* deg    = (int*)(Wt6l + WBIG);   // also scatter cursor
    int* rowptr = deg + N_NODES;         // N_NODES + 1
    int* adj    = rowptr + (N_NODES + 1);

    // fp32 aliases
    float* F32_R0 = (float*)R0h;
    // H0 split planes at head of R1 region
    ushort_t* H0h = R1h;
    ushort_t* H0l = R1h + PLANE64;

    // ---- CSR build ----
    zero_kernel<<<(N_NODES + 255) / 256, 256, 0, stream>>>(deg, N_NODES);
    hist_kernel<<<(N_EDGES + 255) / 256, 256, 0, stream>>>(ei, deg);
    scan_kernel<<<1, 1024, 0, stream>>>(deg, rowptr);
    cursor_init_kernel<<<(N_NODES + 255) / 256, 256, 0, stream>>>(rowptr, deg);
    scatter_kernel<<<(N_EDGES + 255) / 256, 256, 0, stream>>>(ei, deg, adj);

    // ---- weight prep: transpose + split ----
    dim3 wtgS(HIDDEN / 32, IN_F / 32);
    dim3 wtgB(HIDDEN / 32, HIDDEN / 32);
    wtrans_kernel<<<wtgS, 256, 0, stream>>>(W1, Wt1h, Wt1l, IN_F);
    wtrans_kernel<<<wtgB, 256, 0, stream>>>(W2, Wt2h, Wt2l, HIDDEN);
    wtrans_kernel<<<wtgB, 256, 0, stream>>>(W3, Wt3h, Wt3l, HIDDEN);
    wtrans_kernel<<<wtgB, 256, 0, stream>>>(W4, Wt4h, Wt4l, HIDDEN);
    wtrans_kernel<<<wtgB, 256, 0, stream>>>(lin1_W, Wt5h, Wt5l, HIDDEN);
    wtrans_kernel<<<wtgB, 256, 0, stream>>>(lin2_W, Wt6h, Wt6l, HIDDEN);

    const int ngrid = MT * NT;     // 1564 blocks, 1-D swizzled grid
    int nwb = (N_NODES + 3) / 4;   // wave-per-node blocks (4 waves/block)

    // ---- h0 = (1+eps1)*x + gather(x) -> H0 split ----
    gather64_kernel<<<nwb, 256, 0, stream>>>(x, rowptr, adj, eps1, H0h, H0l);

    // h1 = relu(h0 @ W1 + b1) -> R0 split
    gemm_split_kernel<IN_F><<<ngrid, 256, 0, stream>>>(H0h, H0l, Wt1h, Wt1l, b1,
        nullptr, R0h, R0l, 1, nullptr, nullptr, nullptr, nullptr);
    // h2 = relu(h1 @ W2 + b2) -> R1 split
    gemm_split_kernel<HIDDEN><<<ngrid, 256, 0, stream>>>(R0h, R0l, Wt2h, Wt2l, b2,
        nullptr, R1h, R1l, 1, nullptr, nullptr, nullptr, nullptr);
    // h3 = bn1(relu(h2 @ W3 + b3)) -> F32_R0
    gemm_split_kernel<HIDDEN><<<ngrid, 256, 0, stream>>>(R1h, R1l, Wt3h, Wt3l, b3,
        F32_R0, nullptr, nullptr, 2, bn1_g, bn1_b, bn1_m, bn1_v);

    // ---- h4 = (1+eps2)*h3 + gather(h3) -> R1 split (2 waves/node) ----
    gather512_kernel<<<(N_NODES + 1) / 2, 256, 0, stream>>>(F32_R0, rowptr, adj,
                                                            eps2, R1h, R1l);

    // h5 = bn2(relu(h4 @ W4 + b4)) -> R0 split
    gemm_split_kernel<HIDDEN><<<ngrid, 256, 0, stream>>>(R1h, R1l, Wt4h, Wt4l, b4,
        nullptr, R0h, R0l, 2, bn2_g, bn2_b, bn2_m, bn2_v);
    // h6 = relu(h5 @ lin1_W + lin1_b) -> R1 split
    gemm_split_kernel<HIDDEN><<<ngrid, 256, 0, stream>>>(R0h, R0l, Wt5h, Wt5l, lin1_b,
        nullptr, R1h, R1l, 1, nullptr, nullptr, nullptr, nullptr);
    // h7 = h6 @ lin2_W + lin2_b -> F32_R0
    gemm_split_kernel<HIDDEN><<<ngrid, 256, 0, stream>>>(R1h, R1l, Wt6h, Wt6l, lin2_b,
        F32_R0, nullptr, nullptr, 0, nullptr, nullptr, nullptr, nullptr);

    // head
    fc2_kernel<<<(N_TRAIN + 3) / 4, 256, 0, stream>>>(F32_R0, ei, teid, fc2_W, fc2_b,
                                                      (float*)d_out);
}

// Round 9
// 907.338 us; speedup vs baseline: 1.8069x; 1.1422x over previous
//
#include <hip/hip_runtime.h>

#define N_NODES 50000
#define MPAD    50048           // N_NODES rounded up to 128
#define IN_F    64
#define HIDDEN  512
#define N_EDGES 160000
#define N_TRAIN 80000
#define N_CLASS 7
#define BN_EPS  1e-5f

#define MT      (MPAD / 128)    // 391 m-tiles
#define NT      4               // 128-col n-tiles
#define FULLGRP ((MT / 8) * 32) // 1536: full 8-mtile x 4-ntile swizzle groups
#define NBLK    ((N_NODES + 255) / 256)   // 196 scan blocks

typedef short  bf16x8 __attribute__((ext_vector_type(8)));
typedef float  f32x4  __attribute__((ext_vector_type(4)));
typedef unsigned short ushort_t;

// ---- bf16 helpers (manual RNE; values are finite) -------------------------
__device__ __forceinline__ ushort_t f2b(float v) {
    union { float f; unsigned int u; } c; c.f = v;
    unsigned int x = c.u;
    unsigned int r = (x + 0x7FFFu + ((x >> 16) & 1u)) >> 16;
    return (ushort_t)r;
}
__device__ __forceinline__ float b2f(ushort_t b) {
    union { unsigned int u; float f; } c; c.u = ((unsigned int)b) << 16;
    return c.f;
}

// ---- async global->LDS, 16B per lane (dst = wave-uniform base + lane*16) --
__device__ __forceinline__ void async_copy16(const void* g, void* l) {
    __builtin_amdgcn_global_load_lds(
        (const __attribute__((address_space(1))) void*)g,
        (__attribute__((address_space(3))) void*)l, 16, 0, 0);
}

// ===========================================================================
// CSR build: zero -> histogram(dst) -> decoupled scan -> scatter src ids
// (old single-block scan was ~1000 serial barriers on one block)
// ===========================================================================
__global__ void zero_kernel(int* __restrict__ p, int n) {
    int i = blockIdx.x * blockDim.x + threadIdx.x;
    if (i < n) p[i] = 0;
}

__global__ void hist_kernel(const int* __restrict__ ei, int* __restrict__ deg) {
    int e = blockIdx.x * blockDim.x + threadIdx.x;
    if (e >= N_EDGES) return;
    atomicAdd(&deg[ei[N_EDGES + e]], 1);
}

// per-256-chunk sums of deg
__global__ __launch_bounds__(256) void blocksum_kernel(const int* __restrict__ deg,
                                                       int* __restrict__ bsum) {
    __shared__ int s[256];
    int i = blockIdx.x * 256 + threadIdx.x;
    s[threadIdx.x] = (i < N_NODES) ? deg[i] : 0;
    __syncthreads();
    for (int off = 128; off > 0; off >>= 1) {
        if (threadIdx.x < off) s[threadIdx.x] += s[threadIdx.x + off];
        __syncthreads();
    }
    if (threadIdx.x == 0) bsum[blockIdx.x] = s[0];
}

// single block: exclusive scan of NBLK(=196) block sums
__global__ __launch_bounds__(256) void scanbsum_kernel(const int* __restrict__ bsum,
                                                       int* __restrict__ boff) {
    __shared__ int s[256];
    int tid = threadIdx.x;
    s[tid] = (tid < NBLK) ? bsum[tid] : 0;
    __syncthreads();
    for (int off = 1; off < 256; off <<= 1) {
        int t = (tid >= off) ? s[tid - off] : 0;
        __syncthreads();
        s[tid] += t;
        __syncthreads();
    }
    if (tid < NBLK) boff[tid] = (tid == 0) ? 0 : s[tid - 1];
}

// per-block local inclusive scan + block offset -> rowptr and scatter cursor
__global__ __launch_bounds__(256) void rowptr_kernel(const int* __restrict__ deg,
                                                     const int* __restrict__ boff,
                                                     int* __restrict__ rowptr,
                                                     int* __restrict__ cursor) {
    __shared__ int s[256];
    int tid = threadIdx.x;
    int i = blockIdx.x * 256 + tid;
    int d = (i < N_NODES) ? deg[i] : 0;
    s[tid] = d;
    __syncthreads();
    for (int off = 1; off < 256; off <<= 1) {
        int t = (tid >= off) ? s[tid - off] : 0;
        __syncthreads();
        s[tid] += t;
        __syncthreads();
    }
    int incl = s[tid] + boff[blockIdx.x];
    if (i < N_NODES) {
        rowptr[i + 1] = incl;
        cursor[i] = incl - d;   // exclusive prefix = row start
    }
    if (i == 0) rowptr[0] = 0;
}

__global__ void scatter_kernel(const int* __restrict__ ei,
                               int* __restrict__ cursor, int* __restrict__ adj) {
    int e = blockIdx.x * blockDim.x + threadIdx.x;
    if (e >= N_EDGES) return;
    int src = ei[e], dst = ei[N_EDGES + e];
    int pos = atomicAdd(&cursor[dst], 1);
    adj[pos] = src;
}

// ===========================================================================
// Gather aggregation (CSR), fused scale + split-bf16 output.
// out[n] = (1+eps)*h[n] + sum_{k in row n} h[adj[k]]
// ===========================================================================
__global__ __launch_bounds__(256) void gather64_kernel(
    const float* __restrict__ x, const int* __restrict__ rowptr,
    const int* __restrict__ adj, const float* __restrict__ epsp,
    ushort_t* __restrict__ hi, ushort_t* __restrict__ lo) {
    int wave = threadIdx.x >> 6, lane = threadIdx.x & 63;
    int n = blockIdx.x * 4 + wave;
    if (n >= N_NODES) return;
    float s = 1.0f + *epsp;
    float sum = s * x[(size_t)n * IN_F + lane];
    int beg = rowptr[n], end = rowptr[n + 1];
    for (int k = beg; k < end; k++) {
        sum += x[(size_t)adj[k] * IN_F + lane];
    }
    ushort_t hb = f2b(sum);
    ushort_t lb = f2b(sum - b2f(hb));
    hi[(size_t)n * IN_F + lane] = hb;
    lo[(size_t)n * IN_F + lane] = lb;
}

// 2 waves per node (256 features each)
__global__ __launch_bounds__(256) void gather512_kernel(
    const float* __restrict__ h, const int* __restrict__ rowptr,
    const int* __restrict__ adj, const float* __restrict__ epsp,
    ushort_t* __restrict__ hi, ushort_t* __restrict__ lo) {
    int wave = threadIdx.x >> 6, lane = threadIdx.x & 63;
    int n = blockIdx.x * 2 + (wave >> 1);
    if (n >= N_NODES) return;
    float s = 1.0f + *epsp;
    const int f = (wave & 1) * 256 + lane * 4;
    float4 a = *(const float4*)&h[(size_t)n * HIDDEN + f];
    float sum[4] = {s * a.x, s * a.y, s * a.z, s * a.w};
    int beg = rowptr[n], end = rowptr[n + 1];
    for (int k = beg; k < end; k++) {
        float4 b = *(const float4*)&h[(size_t)adj[k] * HIDDEN + f];
        sum[0] += b.x; sum[1] += b.y; sum[2] += b.z; sum[3] += b.w;
    }
    ushort_t h4[4], l4[4];
#pragma unroll
    for (int j = 0; j < 4; j++) {
        h4[j] = f2b(sum[j]);
        l4[j] = f2b(sum[j] - b2f(h4[j]));
    }
    *(ushort4*)&hi[(size_t)n * HIDDEN + f] = make_ushort4(h4[0], h4[1], h4[2], h4[3]);
    *(ushort4*)&lo[(size_t)n * HIDDEN + f] = make_ushort4(l4[0], l4[1], l4[2], l4[3]);
}

// ---------------------------------------------------------------------------
// Batched weight prep: all 6 W[K][512] fp32 -> Wt_hi/lo[512][K] bf16.
// grid (16, 16, 6); z selects weight; z=0 has K=64 (extra kb blocks exit).
// ---------------------------------------------------------------------------
__global__ void wtrans_all_kernel(const float* __restrict__ w0,
                                  const float* __restrict__ w1,
                                  const float* __restrict__ w2,
                                  const float* __restrict__ w3,
                                  const float* __restrict__ w4,
                                  const float* __restrict__ w5,
                                  ushort_t* __restrict__ Wp) {
    const size_t WSMALL = (size_t)HIDDEN * IN_F;
    const size_t WBIG   = (size_t)HIDDEN * HIDDEN;
    int z = blockIdx.z;
    const float* W = (z == 0) ? w0 : (z == 1) ? w1 : (z == 2) ? w2
                   : (z == 3) ? w3 : (z == 4) ? w4 : w5;
    int K = (z == 0) ? IN_F : HIDDEN;
    size_t off_h = (z == 0) ? 0 : 2 * WSMALL + (size_t)(z - 1) * 2 * WBIG;
    ushort_t* Whi = Wp + off_h;
    ushort_t* Wlo = Whi + ((z == 0) ? WSMALL : WBIG);

    __shared__ float t[32][33];
    int tx = threadIdx.x & 31, ty = threadIdx.x >> 5;   // ty 0..7
    int nb = blockIdx.x * 32, kb = blockIdx.y * 32;
    if (kb >= K) return;
#pragma unroll
    for (int i = 0; i < 4; i++) {
        int k = kb + ty + i * 8;
        t[ty + i * 8][tx] = W[(size_t)k * HIDDEN + nb + tx];
    }
    __syncthreads();
#pragma unroll
    for (int i = 0; i < 4; i++) {
        int n = nb + ty + i * 8;
        int k = kb + tx;
        float v = t[tx][ty + i * 8];
        ushort_t hb = f2b(v);
        ushort_t lb = f2b(v - b2f(hb));
        Whi[(size_t)n * K + k] = hb;
        Wlo[(size_t)n * K + k] = lb;
    }
}

// ---------------------------------------------------------------------------
// Split-bf16 MFMA GEMM (K=512): single-buffer LDS + verified swizzle
// (R8 structure: best measured; R6 no-LDS and R7 dbuf both regressed).
// ---------------------------------------------------------------------------
template<int K>
__global__ __launch_bounds__(256) void gemm_split_kernel(
    const ushort_t* __restrict__ Ahi, const ushort_t* __restrict__ Alo,
    const ushort_t* __restrict__ Bhi, const ushort_t* __restrict__ Blo,
    const float* __restrict__ bias,
    float* __restrict__ Cf, ushort_t* __restrict__ Chi, ushort_t* __restrict__ Clo,
    int mode,
    const float* __restrict__ bn_g, const float* __restrict__ bn_b,
    const float* __restrict__ bn_m, const float* __restrict__ bn_v) {
    __shared__ ushort_t As_h[128 * 32];
    __shared__ ushort_t As_l[128 * 32];
    __shared__ ushort_t Bs_h[128 * 32];
    __shared__ ushort_t Bs_l[128 * 32];

    const int tid  = threadIdx.x;
    const int wave = tid >> 6, lane = tid & 63;
    const int wm = wave >> 1, wn = wave & 1;
    const int quad = lane >> 4, r = lane & 15;

    int idx = blockIdx.x, m_t, n_t;
    if (idx < FULLGRP) {
        m_t = (idx >> 5) * 8 + (idx & 7);
        n_t = (idx >> 3) & 3;
    } else {
        int t = idx - FULLGRP;
        m_t = (FULLGRP >> 2) + (t >> 2);
        n_t = t & 3;
    }
    const int m0 = m_t * 128, n0 = n_t * 128;

    const f32x4 vzero = {0.f, 0.f, 0.f, 0.f};
    f32x4 acc[4][4];
#pragma unroll
    for (int i = 0; i < 4; i++)
#pragma unroll
        for (int j = 0; j < 4; j++) acc[i][j] = vzero;

    const int srow = lane >> 2;
    const int scol = (((lane & 3) + ((srow >> 1) & 3)) & 3) * 8;
    const int csw  = ((quad - ((r >> 1) & 3)) & 3) * 8;

    for (int k0 = 0; k0 < K; k0 += 32) {
        __syncthreads();
#pragma unroll
        for (int tt = 0; tt < 2; tt++) {
            int rr = wave * 32 + tt * 16 + srow;
            int lbase = (wave * 32 + tt * 16) * 32;
            size_t ga = (size_t)(m0 + rr) * K + k0 + scol;
            size_t gb = (size_t)(n0 + rr) * K + k0 + scol;
            async_copy16(Ahi + ga, &As_h[lbase]);
            async_copy16(Alo + ga, &As_l[lbase]);
            async_copy16(Bhi + gb, &Bs_h[lbase]);
            async_copy16(Blo + gb, &Bs_l[lbase]);
        }
        __syncthreads();

        bf16x8 ah[4], al[4], bh[4], bl[4];
#pragma unroll
        for (int i = 0; i < 4; i++) {
            int aofs = (wm * 64 + i * 16 + r) * 32 + csw;
            int bofs = (wn * 64 + i * 16 + r) * 32 + csw;
            ah[i] = *(const bf16x8*)&As_h[aofs];
            al[i] = *(const bf16x8*)&As_l[aofs];
            bh[i] = *(const bf16x8*)&Bs_h[bofs];
            bl[i] = *(const bf16x8*)&Bs_l[bofs];
        }
#pragma unroll
        for (int i = 0; i < 4; i++)
#pragma unroll
            for (int j = 0; j < 4; j++) {
                acc[i][j] = __builtin_amdgcn_mfma_f32_16x16x32_bf16(ah[i], bh[j], acc[i][j], 0, 0, 0);
                acc[i][j] = __builtin_amdgcn_mfma_f32_16x16x32_bf16(ah[i], bl[j], acc[i][j], 0, 0, 0);
                acc[i][j] = __builtin_amdgcn_mfma_f32_16x16x32_bf16(al[i], bh[j], acc[i][j], 0, 0, 0);
            }
    }

    float bia[4], sc[4], sh[4];
#pragma unroll
    for (int j = 0; j < 4; j++) {
        int col = n0 + wn * 64 + j * 16 + r;
        bia[j] = bias[col];
        if (mode == 2) {
            float g = bn_g[col], bb = bn_b[col], mm = bn_m[col], vv = bn_v[col];
            sc[j] = g * rsqrtf(vv + BN_EPS);
            sh[j] = bb - mm * sc[j];
        } else { sc[j] = 1.f; sh[j] = 0.f; }
    }
#pragma unroll
    for (int i = 0; i < 4; i++) {
#pragma unroll
        for (int rg = 0; rg < 4; rg++) {
            int row = m0 + wm * 64 + i * 16 + quad * 4 + rg;
            if (row >= N_NODES) continue;
#pragma unroll
            for (int j = 0; j < 4; j++) {
                int col = n0 + wn * 64 + j * 16 + r;
                float v = acc[i][j][rg] + bia[j];
                if (mode >= 1) v = fmaxf(v, 0.f);
                if (mode == 2) v = v * sc[j] + sh[j];
                size_t oix = (size_t)row * HIDDEN + col;
                if (Cf) {
                    Cf[oix] = v;
                } else {
                    ushort_t hb = f2b(v);
                    ushort_t lb = f2b(v - b2f(hb));
                    Chi[oix] = hb;
                    Clo[oix] = lb;
                }
            }
        }
    }
}

// ---------------------------------------------------------------------------
// K=64 specialized GEMM: whole K staged once in 64 KB LDS, ONE barrier total
// (vs 4 in the looped version). Row = 128 B = 8 chunks of 16 B; swizzle
// rotates chunk by (row&7) (applied to global src; read inverts).
// Output: relu + split planes (gemm1's only mode).
// ---------------------------------------------------------------------------
__global__ __launch_bounds__(256) void gemm_k64_kernel(
    const ushort_t* __restrict__ Ahi, const ushort_t* __restrict__ Alo,
    const ushort_t* __restrict__ Bhi, const ushort_t* __restrict__ Blo,
    const float* __restrict__ bias,
    ushort_t* __restrict__ Chi, ushort_t* __restrict__ Clo) {
    const int K = 64;
    __shared__ ushort_t As_h[128 * 64];
    __shared__ ushort_t As_l[128 * 64];
    __shared__ ushort_t Bs_h[128 * 64];
    __shared__ ushort_t Bs_l[128 * 64];

    const int tid  = threadIdx.x;
    const int wave = tid >> 6, lane = tid & 63;
    const int wm = wave >> 1, wn = wave & 1;
    const int quad = lane >> 4, r = lane & 15;

    int idx = blockIdx.x, m_t, n_t;
    if (idx < FULLGRP) {
        m_t = (idx >> 5) * 8 + (idx & 7);
        n_t = (idx >> 3) & 3;
    } else {
        int t = idx - FULLGRP;
        m_t = (FULLGRP >> 2) + (t >> 2);
        n_t = t & 3;
    }
    const int m0 = m_t * 128, n0 = n_t * 128;

    // staging: each instr covers 8 rows x 128 B; lane row = base+(lane>>3),
    // dst chunk = lane&7; src chunk = (dst - row) & 7  (row&7 == lane>>3)
    const int srow8 = lane >> 3;                       // 0..7
    const int sc8   = (((lane & 7) - srow8) & 7) * 8;  // src elem offset
#pragma unroll
    for (int t = 0; t < 4; t++) {
        int base = wave * 32 + t * 8;
        int rr = base + srow8;
        int lbase = base * 64;
        size_t ga = (size_t)(m0 + rr) * K + sc8;
        size_t gb = (size_t)(n0 + rr) * K + sc8;
        async_copy16(Ahi + ga, &As_h[lbase]);
        async_copy16(Alo + ga, &As_l[lbase]);
        async_copy16(Bhi + gb, &Bs_h[lbase]);
        async_copy16(Blo + gb, &Bs_l[lbase]);
    }
    __syncthreads();   // single barrier: drain DMA, then compute

    const f32x4 vzero = {0.f, 0.f, 0.f, 0.f};
    f32x4 acc[4][4];
#pragma unroll
    for (int i = 0; i < 4; i++)
#pragma unroll
        for (int j = 0; j < 4; j++) acc[i][j] = vzero;

#pragma unroll
    for (int ks = 0; ks < 2; ks++) {           // two 32-k chunks
        bf16x8 ah[4], al[4], bh[4], bl[4];
#pragma unroll
        for (int i = 0; i < 4; i++) {
            int ra = wm * 64 + i * 16 + r;
            int rb = wn * 64 + i * 16 + r;
            int ca = ((quad + ks * 4 + (ra & 7)) & 7) * 8;
            int cb = ((quad + ks * 4 + (rb & 7)) & 7) * 8;
            ah[i] = *(const bf16x8*)&As_h[ra * 64 + ca];
            al[i] = *(const bf16x8*)&As_l[ra * 64 + ca];
            bh[i] = *(const bf16x8*)&Bs_h[rb * 64 + cb];
            bl[i] = *(const bf16x8*)&Bs_l[rb * 64 + cb];
        }
#pragma unroll
        for (int i = 0; i < 4; i++)
#pragma unroll
            for (int j = 0; j < 4; j++) {
                acc[i][j] = __builtin_amdgcn_mfma_f32_16x16x32_bf16(ah[i], bh[j], acc[i][j], 0, 0, 0);
                acc[i][j] = __builtin_amdgcn_mfma_f32_16x16x32_bf16(ah[i], bl[j], acc[i][j], 0, 0, 0);
                acc[i][j] = __builtin_amdgcn_mfma_f32_16x16x32_bf16(al[i], bh[j], acc[i][j], 0, 0, 0);
            }
    }

    float bia[4];
#pragma unroll
    for (int j = 0; j < 4; j++) bia[j] = bias[n0 + wn * 64 + j * 16 + r];
#pragma unroll
    for (int i = 0; i < 4; i++) {
#pragma unroll
        for (int rg = 0; rg < 4; rg++) {
            int row = m0 + wm * 64 + i * 16 + quad * 4 + rg;
            if (row >= N_NODES) continue;
#pragma unroll
            for (int j = 0; j < 4; j++) {
                int col = n0 + wn * 64 + j * 16 + r;
                float v = fmaxf(acc[i][j][rg] + bia[j], 0.f);
                size_t oix = (size_t)row * HIDDEN + col;
                ushort_t hb = f2b(v);
                ushort_t lb = f2b(v - b2f(hb));
                Chi[oix] = hb;
                Clo[oix] = lb;
            }
        }
    }
}

// ---------------------------------------------------------------------------
// out[t] = (h[a_t] * h[b_t]) @ fc2_W + fc2_b ; one wave per train edge.
// ---------------------------------------------------------------------------
__global__ __launch_bounds__(256) void fc2_kernel(
    const float* __restrict__ h, const int* __restrict__ ei,
    const int* __restrict__ teid, const float* __restrict__ W,
    const float* __restrict__ bias, float* __restrict__ out) {
    __shared__ float Ws[HIDDEN * N_CLASS];
    __shared__ float bs[N_CLASS];
    for (int i = threadIdx.x; i < HIDDEN * N_CLASS; i += blockDim.x) Ws[i] = W[i];
    if (threadIdx.x < N_CLASS) bs[threadIdx.x] = bias[threadIdx.x];
    __syncthreads();

    int wave = threadIdx.x >> 6;
    int lane = threadIdx.x & 63;
    int t = blockIdx.x * 4 + wave;
    if (t >= N_TRAIN) return;

    int e = teid[t];
    int a = ei[e];
    int b = ei[N_EDGES + e];
    const float* xa = h + (size_t)a * HIDDEN;
    const float* xb = h + (size_t)b * HIDDEN;

    float acc[N_CLASS];
#pragma unroll
    for (int c = 0; c < N_CLASS; c++) acc[c] = 0.f;

    int j0 = lane * 8;
    float4 a0 = *(const float4*)&xa[j0];
    float4 a1 = *(const float4*)&xa[j0 + 4];
    float4 b0 = *(const float4*)&xb[j0];
    float4 b1 = *(const float4*)&xb[j0 + 4];
    float p[8] = {a0.x * b0.x, a0.y * b0.y, a0.z * b0.z, a0.w * b0.w,
                  a1.x * b1.x, a1.y * b1.y, a1.z * b1.z, a1.w * b1.w};
#pragma unroll
    for (int jj = 0; jj < 8; jj++) {
        const float* wrow = &Ws[(j0 + jj) * N_CLASS];
#pragma unroll
        for (int c = 0; c < N_CLASS; c++) acc[c] = fmaf(p[jj], wrow[c], acc[c]);
    }
#pragma unroll
    for (int c = 0; c < N_CLASS; c++) {
        float v = acc[c];
        for (int off = 32; off > 0; off >>= 1) v += __shfl_down(v, off, 64);
        if (lane == 0) out[(size_t)t * N_CLASS + c] = v + bs[c];
    }
}

// ---------------------------------------------------------------------------
extern "C" void kernel_launch(void* const* d_in, const int* in_sizes, int n_in,
                              void* d_out, int out_size, void* d_ws, size_t ws_size,
                              hipStream_t stream) {
    const float* x      = (const float*)d_in[0];
    const int*   ei     = (const int*)d_in[1];
    const int*   teid   = (const int*)d_in[2];
    const float* W1     = (const float*)d_in[3];
    const float* b1     = (const float*)d_in[4];
    const float* W2     = (const float*)d_in[5];
    const float* b2     = (const float*)d_in[6];
    const float* W3     = (const float*)d_in[7];
    const float* b3     = (const float*)d_in[8];
    const float* bn1_g  = (const float*)d_in[9];
    const float* bn1_b  = (const float*)d_in[10];
    const float* bn1_m  = (const float*)d_in[11];
    const float* bn1_v  = (const float*)d_in[12];
    const float* eps1   = (const float*)d_in[13];
    const float* W4     = (const float*)d_in[14];
    const float* b4     = (const float*)d_in[15];
    const float* bn2_g  = (const float*)d_in[16];
    const float* bn2_b  = (const float*)d_in[17];
    const float* bn2_m  = (const float*)d_in[18];
    const float* bn2_v  = (const float*)d_in[19];
    const float* eps2   = (const float*)d_in[20];
    const float* lin1_W = (const float*)d_in[21];
    const float* lin1_b = (const float*)d_in[22];
    const float* lin2_W = (const float*)d_in[23];
    const float* lin2_b = (const float*)d_in[24];
    const float* fc2_W  = (const float*)d_in[25];
    const float* fc2_b  = (const float*)d_in[26];

    const size_t PLANE   = (size_t)MPAD * HIDDEN;
    const size_t PLANE64 = (size_t)MPAD * IN_F;

    ushort_t* R0h = (ushort_t*)d_ws;
    ushort_t* R0l = R0h + PLANE;
    ushort_t* R1h = R0l + PLANE;
    ushort_t* R1l = R1h + PLANE;

    const size_t WSMALL = (size_t)HIDDEN * IN_F;
    const size_t WBIG   = (size_t)HIDDEN * HIDDEN;
    ushort_t* Wp   = R1l + PLANE;
    ushort_t* Wt1h = Wp;            ushort_t* Wt1l = Wt1h + WSMALL;
    ushort_t* Wt2h = Wt1l + WSMALL; ushort_t* Wt2l = Wt2h + WBIG;
    ushort_t* Wt3h = Wt2l + WBIG;   ushort_t* Wt3l = Wt3h + WBIG;
    ushort_t* Wt4h = Wt3l + WBIG;   ushort_t* Wt4l = Wt4h + WBIG;
    ushort_t* Wt5h = Wt4l + WBIG;   ushort_t* Wt5l = Wt5h + WBIG;
    ushort_t* Wt6h = Wt5l + WBIG;   ushort_t* Wt6l = Wt6h + WBIG;

    // CSR arrays (ints) after weights
    int* deg    = (int*)(Wt6l + WBIG);
    int* cursor = deg + N_NODES;
    int* rowptr = cursor + N_NODES;        // N_NODES + 1
    int* bsum   = rowptr + (N_NODES + 1);  // NBLK
    int* boff   = bsum + NBLK;             // NBLK
    int* adj    = boff + NBLK;             // N_EDGES

    // fp32 aliases
    float* F32_R0 = (float*)R0h;
    ushort_t* H0h = R1h;
    ushort_t* H0l = R1h + PLANE64;

    // ---- CSR build (decoupled scan) ----
    zero_kernel<<<(N_NODES + 255) / 256, 256, 0, stream>>>(deg, N_NODES);
    hist_kernel<<<(N_EDGES + 255) / 256, 256, 0, stream>>>(ei, deg);
    blocksum_kernel<<<NBLK, 256, 0, stream>>>(deg, bsum);
    scanbsum_kernel<<<1, 256, 0, stream>>>(bsum, boff);
    rowptr_kernel<<<NBLK, 256, 0, stream>>>(deg, boff, rowptr, cursor);
    scatter_kernel<<<(N_EDGES + 255) / 256, 256, 0, stream>>>(ei, cursor, adj);

    // ---- weight prep: one batched launch ----
    wtrans_all_kernel<<<dim3(16, 16, 6), 256, 0, stream>>>(W1, W2, W3, W4,
                                                           lin1_W, lin2_W, Wp);

    const int ngrid = MT * NT;     // 1564 blocks, 1-D swizzled grid
    int nwb = (N_NODES + 3) / 4;

    // ---- h0 = (1+eps1)*x + gather(x) -> H0 split ----
    gather64_kernel<<<nwb, 256, 0, stream>>>(x, rowptr, adj, eps1, H0h, H0l);

    // h1 = relu(h0 @ W1 + b1) -> R0 split  (K=64 single-stage kernel)
    gemm_k64_kernel<<<ngrid, 256, 0, stream>>>(H0h, H0l, Wt1h, Wt1l, b1, R0h, R0l);
    // h2 = relu(h1 @ W2 + b2) -> R1 split
    gemm_split_kernel<HIDDEN><<<ngrid, 256, 0, stream>>>(R0h, R0l, Wt2h, Wt2l, b2,
        nullptr, R1h, R1l, 1, nullptr, nullptr, nullptr, nullptr);
    // h3 = bn1(relu(h2 @ W3 + b3)) -> F32_R0
    gemm_split_kernel<HIDDEN><<<ngrid, 256, 0, stream>>>(R1h, R1l, Wt3h, Wt3l, b3,
        F32_R0, nullptr, nullptr, 2, bn1_g, bn1_b, bn1_m, bn1_v);

    // ---- h4 = (1+eps2)*h3 + gather(h3) -> R1 split (2 waves/node) ----
    gather512_kernel<<<(N_NODES + 1) / 2, 256, 0, stream>>>(F32_R0, rowptr, adj,
                                                            eps2, R1h, R1l);

    // h5 = bn2(relu(h4 @ W4 + b4)) -> R0 split
    gemm_split_kernel<HIDDEN><<<ngrid, 256, 0, stream>>>(R1h, R1l, Wt4h, Wt4l, b4,
        nullptr, R0h, R0l, 2, bn2_g, bn2_b, bn2_m, bn2_v);
    // h6 = relu(h5 @ lin1_W + lin1_b) -> R1 split
    gemm_split_kernel<HIDDEN><<<ngrid, 256, 0, stream>>>(R0h, R0l, Wt5h, Wt5l, lin1_b,
        nullptr, R1h, R1l, 1, nullptr, nullptr, nullptr, nullptr);
    // h7 = h6 @ lin2_W + lin2_b -> F32_R0
    gemm_split_kernel<HIDDEN><<<ngrid, 256, 0, stream>>>(R1h, R1l, Wt6h, Wt6l, lin2_b,
        F32_R0, nullptr, nullptr, 0, nullptr, nullptr, nullptr, nullptr);

    // head
    fc2_kernel<<<(N_TRAIN + 3) / 4, 256, 0, stream>>>(F32_R0, ei, teid, fc2_W, fc2_b,
                                                      (float*)d_out);
}